// Round 15
// baseline (251.316 us; speedup 1.0000x reference)
//
#include <hip/hip_runtime.h>

typedef unsigned short u16;
typedef u16 u16x8 __attribute__((ext_vector_type(8)));
typedef __bf16 bf16x8 __attribute__((ext_vector_type(8)));
typedef float f32x4 __attribute__((ext_vector_type(4)));
typedef unsigned u32x2 __attribute__((ext_vector_type(2)));

#define T_TOK 1024
#define H_DIM 2048
#define E_NUM 16
#define I_DIM 704
#define IS_DIM 1408

#define MFMA(a, b, c) __builtin_amdgcn_mfma_f32_16x16x32_bf16(a, b, c, 0, 0, 0)

__device__ __forceinline__ u16 f2bf(float f) {
  union { float f; unsigned u; } v; v.f = f;
  unsigned r = v.u + 0x7fffu + ((v.u >> 16) & 1u);
  return (u16)(r >> 16);
}

// async global->LDS 16B per lane; dest linear (wave-uniform base + lane*16)
__device__ __forceinline__ void gload16(const void* g, void* l) {
  __builtin_amdgcn_global_load_lds(
      (const __attribute__((address_space(1))) unsigned int*)g,
      (__attribute__((address_space(3))) unsigned int*)l, 16, 0, 0);
}

// Swizzled LDS read address within 128-byte rows: XOR bits[6:4] with (row&7).
__device__ __forceinline__ const char* lds_sw(const u16* base, int row, int kByte) {
  return (const char*)base + row * 128 + (kByte ^ ((row & 7) << 4));
}

// ---------------- transpose+convert tile body: [R][C] f32 -> [C][R] bf16 ----------------
// TR rows x 128 cols per block. Each thread loads a ROW-PAIR (2x f32x4, long
// contiguous 512B/row runs, TR/16*2 independent loads), packs 2 rows into u32
// bf16-pairs in LDS [TR/2][130] u32, then streams 256B-contiguous wave writes.
template <int TR>
__device__ __forceinline__ void transp_tile_body(const float* __restrict__ in,
                                                 u16* __restrict__ outp, int R, int C,
                                                 int cx, int ry, int z, char* SM) {
  unsigned (*tile)[130] = (unsigned(*)[130])SM;
  const size_t base = (size_t)z * (size_t)R * C;
  const int c0 = cx * 128, r0 = ry * TR;
  const int tid = threadIdx.x;
  const int rp0 = tid >> 5, cc = tid & 31;
#pragma unroll
  for (int j = 0; j < TR / 16; ++j) {
    const int rp = j * 8 + rp0;
    const float* p0 = in + base + (size_t)(r0 + 2 * rp) * C + c0 + cc * 4;
    const f32x4 v0 = *(const f32x4*)(p0);
    const f32x4 v1 = *(const f32x4*)(p0 + C);
    u32x2 wa, wb;
    wa[0] = (unsigned)f2bf(v0[0]) | ((unsigned)f2bf(v1[0]) << 16);
    wa[1] = (unsigned)f2bf(v0[1]) | ((unsigned)f2bf(v1[1]) << 16);
    wb[0] = (unsigned)f2bf(v0[2]) | ((unsigned)f2bf(v1[2]) << 16);
    wb[1] = (unsigned)f2bf(v0[3]) | ((unsigned)f2bf(v1[3]) << 16);
    *(u32x2*)&tile[rp][cc * 4] = wa;
    *(u32x2*)&tile[rp][cc * 4 + 2] = wb;
  }
  __syncthreads();
#pragma unroll
  for (int i = 0; i < TR / 4; ++i) {
    const int idx = i * 256 + tid;
    const int oc = idx / (TR / 2), pr = idx % (TR / 2);
    *(unsigned*)&outp[base + (size_t)(c0 + oc) * R + r0 + 2 * pr] = tile[pr][oc];
  }
}

// ---------------- router body (one block per token) + x->bf16 convert ----------------
__device__ __forceinline__ void router_body(const float* __restrict__ x,
                                            const float* __restrict__ wg,
                                            float* __restrict__ comb,
                                            u16* __restrict__ XB, int t, char* SM) {
  const int tid = threadIdx.x;
  const float* xr = x + (size_t)t * H_DIM;
  const int h0 = tid * 8;
  f32x4 a = *(const f32x4*)(xr + h0);
  f32x4 b = *(const f32x4*)(xr + h0 + 4);
  u16x8 o;
  o[0] = f2bf(a[0]); o[1] = f2bf(a[1]); o[2] = f2bf(a[2]); o[3] = f2bf(a[3]);
  o[4] = f2bf(b[0]); o[5] = f2bf(b[1]); o[6] = f2bf(b[2]); o[7] = f2bf(b[3]);
  *(u16x8*)(XB + (size_t)t * H_DIM + h0) = o;

  float acc[E_NUM];
#pragma unroll
  for (int e = 0; e < E_NUM; ++e) acc[e] = 0.f;
#pragma unroll
  for (int j = 0; j < 8; ++j) {
    const float xv = j < 4 ? a[j] : b[j - 4];
    const f32x4* wr = (const f32x4*)(wg + (size_t)(h0 + j) * E_NUM);
#pragma unroll
    for (int q = 0; q < 4; ++q) {
      f32x4 w4 = wr[q];
      acc[q * 4 + 0] += xv * w4[0];
      acc[q * 4 + 1] += xv * w4[1];
      acc[q * 4 + 2] += xv * w4[2];
      acc[q * 4 + 3] += xv * w4[3];
    }
  }
#pragma unroll
  for (int e = 0; e < E_NUM; ++e)
    for (int off = 32; off > 0; off >>= 1) acc[e] += __shfl_down(acc[e], off);
  float (*part)[E_NUM] = (float(*)[E_NUM])SM;
  if ((tid & 63) == 0) {
#pragma unroll
    for (int e = 0; e < E_NUM; ++e) part[tid >> 6][e] = acc[e];
  }
  __syncthreads();
  if (tid == 0) {
    float p[E_NUM];
    float mx = -1e30f;
    for (int e = 0; e < E_NUM; ++e) {
      p[e] = part[0][e] + part[1][e] + part[2][e] + part[3][e];
      mx = fmaxf(mx, p[e]);
    }
    float s = 0.f;
    for (int e = 0; e < E_NUM; ++e) { p[e] = __expf(p[e] - mx); s += p[e]; }
    const float invs = 1.f / s;
    for (int e = 0; e < E_NUM; ++e) p[e] *= invs;
    float gs[4];
    for (int g = 0; g < 4; ++g)
      gs[g] = fmaxf(fmaxf(p[4 * g], p[4 * g + 1]), fmaxf(p[4 * g + 2], p[4 * g + 3]));
    int g1 = 0;
    for (int g = 1; g < 4; ++g) if (gs[g] > gs[g1]) g1 = g;
    int g2 = -1;
    for (int g = 0; g < 4; ++g) {
      if (g == g1) continue;
      if (g2 < 0 || gs[g] > gs[g2]) g2 = g;
    }
    float m2[E_NUM], cw[E_NUM];
    for (int e = 0; e < E_NUM; ++e) {
      int g = e >> 2;
      m2[e] = (g == g1 || g == g2) ? p[e] : 0.f;
      cw[e] = 0.f;
    }
    float sum6 = 0.f;
    for (int k = 0; k < 6; ++k) {
      int bi = 0; float bv = -1.f;
      for (int e = 0; e < E_NUM; ++e)
        if (m2[e] > bv) { bv = m2[e]; bi = e; }
      cw[bi] = bv; sum6 += bv; m2[bi] = -2.f;
    }
    const float scale = 2.5f / sum6;
    for (int e = 0; e < E_NUM; ++e) comb[t * E_NUM + e] = cw[e] * scale;
  }
}

// ---------------- fused pre-pass: router + out-zero + wgu/wsgu transposes ----------------
#define FP_ROUTER T_TOK                 /* 1024 */
#define FP_ZERO 512                     /* 8.4MB out zero */
#define FP_WGU (11 * 16 * 16)           /* 2816: wgu 128x128 tiles */
#define FP_WSGU (22 * 16)               /* 352:  wsgu 128x128 tiles */
__global__ __launch_bounds__(256) void fused_pre_k(
    const float* __restrict__ x, const float* __restrict__ wg,
    float* __restrict__ comb, u16* __restrict__ XB,
    const float* __restrict__ wgu, const float* __restrict__ wsgu,
    u16* __restrict__ WGUT, u16* __restrict__ WSGUT, float* __restrict__ outz) {
  __shared__ __align__(16) char SM[33280];
  const int bid = blockIdx.x;
  if (bid < FP_ROUTER) {
    router_body(x, wg, comb, XB, bid, SM);
  } else if (bid < FP_ROUTER + FP_ZERO) {
    const int i = ((bid - FP_ROUTER) * 256 + threadIdx.x) * 16;
    const f32x4 z = {0.f, 0.f, 0.f, 0.f};
#pragma unroll
    for (int j = 0; j < 4; ++j) *(f32x4*)(outz + i + j * 4) = z;
  } else if (bid < FP_ROUTER + FP_ZERO + FP_WGU) {
    const int id = bid - FP_ROUTER - FP_ZERO;
    transp_tile_body<128>(wgu, WGUT, H_DIM, 2 * I_DIM, id % 11, (id / 11) % 16,
                          id / 176, SM);
  } else {
    const int id = bid - FP_ROUTER - FP_ZERO - FP_WGU;
    transp_tile_body<128>(wsgu, WSGUT, H_DIM, 2 * IS_DIM, id % 22, id / 22, 0, SM);
  }
}

// ---------------- dispatch: per-expert ordered token lists (no atomics) ----------------
__global__ __launch_bounds__(256) void dispatch_k(const float* __restrict__ comb,
                                                  int* __restrict__ cnt,
                                                  int* __restrict__ tok) {
  const int e = blockIdx.x;
  const int tid = threadIdx.x;
  const int lane = tid & 63, wid = tid >> 6;
  __shared__ int wtot[4];
  int running = 0;
  for (int chunk = 0; chunk < T_TOK / 256; ++chunk) {
    const int t = chunk * 256 + tid;
    const bool sel = comb[t * E_NUM + e] > 0.f;
    unsigned long long mask = __ballot(sel);
    const int pre = __popcll(mask & ((1ull << lane) - 1ull));
    if (lane == 0) wtot[wid] = __popcll(mask);
    __syncthreads();
    int wbase = running;
    for (int w = 0; w < wid; ++w) wbase += wtot[w];
    if (sel) tok[e * T_TOK + wbase + pre] = t;
    running += wtot[0] + wtot[1] + wtot[2] + wtot[3];
    __syncthreads();
  }
  if (tid == 0) cnt[e] = running;
}

// ---------------- fused gate/up GEMM body (m97 structure; 32KB LDS) ----------------
__device__ __forceinline__ void gu_body(
    const u16* __restrict__ A, const u16* __restrict__ Bt,
    const float* __restrict__ comb, const int* __restrict__ cnt,
    const int* __restrict__ tok, u16* __restrict__ outp,
    int gu_off, long long bt_e_stride, long long out_e_stride, int out_stride,
    int bx, int by, int e, char* SM) {
  const int M = cnt ? cnt[e] : T_TOK;
  const int m0 = by * 128;
  if (m0 >= M) return;
  u16* S = (u16*)SM; // As 8192, Bg 4096, Bu 4096 (u16 counts) = 32768 B

  const int n0 = bx * 64;
  const u16* Bte = Bt + (size_t)e * bt_e_stride;
  const u16* Bgp = Bte + (size_t)n0 * H_DIM;
  const u16* Bup = Bte + (size_t)(gu_off + n0) * H_DIM;
  const int tid = threadIdx.x;
  const int w = tid >> 6, l = tid & 63;
  const int r8 = l >> 3;
  const int sk = ((l & 7) ^ r8) * 8; // inverse-swizzled source k offset (elems)

  size_t arow[4];
#pragma unroll
  for (int j = 0; j < 4; ++j) {
    const int m = m0 + w * 32 + j * 8 + r8;
    const int mc = m < M ? m : M - 1;
    const int t = tok ? tok[e * T_TOK + mc] : mc;
    arow[j] = (size_t)t * H_DIM + sk;
  }

  const int wr = tid >> 7;
  const int wc = (tid >> 6) & 1;
  const int fr = l & 15;
  const int fg = l >> 4;

  const f32x4 zero = {0.f, 0.f, 0.f, 0.f};
  f32x4 accg[4][2], accu[4][2];
#pragma unroll
  for (int i = 0; i < 4; ++i)
#pragma unroll
    for (int j = 0; j < 2; ++j) { accg[i][j] = zero; accu[i][j] = zero; }

  for (int kt = 0; kt < H_DIM / 64; ++kt) {
    const int k0 = kt * 64;
#pragma unroll
    for (int j = 0; j < 4; ++j)
      gload16(A + arow[j] + k0, S + (w * 4 + j) * 512);
#pragma unroll
    for (int j = 0; j < 2; ++j) {
      const size_t br = (size_t)(w * 16 + j * 8 + r8) * H_DIM + sk + k0;
      gload16(Bgp + br, S + 8192 + (w * 2 + j) * 512);
      gload16(Bup + br, S + 12288 + (w * 2 + j) * 512);
    }
    __syncthreads();
    const u16* AsC = S;
    const u16* BgC = S + 8192;
    const u16* BuC = S + 12288;
#pragma unroll
    for (int kk = 0; kk < 2; ++kk) {
      const int kb = kk * 64 + fg * 16;
      bf16x8 af[4], bg[2], bu[2];
#pragma unroll
      for (int mi = 0; mi < 4; ++mi)
        af[mi] = *(const bf16x8*)lds_sw(AsC, wr * 64 + mi * 16 + fr, kb);
#pragma unroll
      for (int ni = 0; ni < 2; ++ni) {
        bg[ni] = *(const bf16x8*)lds_sw(BgC, wc * 32 + ni * 16 + fr, kb);
        bu[ni] = *(const bf16x8*)lds_sw(BuC, wc * 32 + ni * 16 + fr, kb);
      }
#pragma unroll
      for (int mi = 0; mi < 4; ++mi)
#pragma unroll
        for (int ni = 0; ni < 2; ++ni) {
          accg[mi][ni] = MFMA(af[mi], bg[ni], accg[mi][ni]);
          accu[mi][ni] = MFMA(af[mi], bu[ni], accu[mi][ni]);
        }
    }
    __syncthreads();
  }

  const int colb = n0 + wc * 32;
#pragma unroll
  for (int mi = 0; mi < 4; ++mi) {
#pragma unroll
    for (int r = 0; r < 4; ++r) {
      const int ml = wr * 64 + mi * 16 + fg * 4 + r;
      if (m0 + ml >= M) continue;
      const int trow = tok ? tok[e * T_TOK + m0 + ml] : (m0 + ml);
      const float wgt = comb ? comb[trow * E_NUM + e] : 1.0f;
      const size_t rowoff = (size_t)e * out_e_stride + (size_t)(m0 + ml) * out_stride;
#pragma unroll
      for (int ni = 0; ni < 2; ++ni) {
        float g = accg[mi][ni][r];
        float u = accu[mi][ni][r];
        float sg = g / (1.f + __expf(-g));
        outp[rowoff + colb + ni * 16 + fr] = f2bf(sg * u * wgt);
      }
    }
  }
}

// ---------------- mega kernel: gu_routed + gu_shared + transp(wd) + transp(wsd) ----------------
// Sequential block order (GEMM ids first): GEMM blocks pack CUs densely at the
// start (cross-block wave overlap), transposes fill behind. Do NOT interleave.
#define MG_GUR_BLKS (11 * 8 * 16) /* 1408 */
#define MG_GUS_BLKS (22 * 8)      /* 176  */
#define MG_TWD_BLKS (16 * 11 * 16)/* 2816: wd 64x128 tiles */
#define MG_TWSD_BLKS (16 * 11)    /* 176:  wsd 128x128 tiles */
__global__ __launch_bounds__(256, 4) void mega_k(
    const u16* __restrict__ XB, const u16* __restrict__ WGUT,
    const u16* __restrict__ WSGUT, const float* __restrict__ comb,
    const int* __restrict__ cnt, const int* __restrict__ tok,
    u16* __restrict__ ACTC, u16* __restrict__ ACTS,
    const float* __restrict__ wd, const float* __restrict__ wsd,
    u16* __restrict__ WDT, u16* __restrict__ WSDT) {
  __shared__ __align__(16) char SM[33280];
  const int bid = blockIdx.x;
  if (bid < MG_GUR_BLKS) {
    gu_body(XB, WGUT, comb, cnt, tok, ACTC, I_DIM, (long long)(2 * I_DIM) * H_DIM,
            (long long)T_TOK * I_DIM, I_DIM, bid % 11, (bid / 11) % 8, bid / 88, SM);
  } else if (bid < MG_GUR_BLKS + MG_GUS_BLKS) {
    const int id = bid - MG_GUR_BLKS;
    gu_body(XB, WSGUT, nullptr, nullptr, nullptr, ACTS, IS_DIM, 0, 0, IS_DIM,
            id % 22, id / 22, 0, SM);
  } else if (bid < MG_GUR_BLKS + MG_GUS_BLKS + MG_TWD_BLKS) {
    const int id = bid - MG_GUR_BLKS - MG_GUS_BLKS;
    transp_tile_body<64>(wd, WDT, I_DIM, H_DIM, id % 16, (id / 16) % 11,
                         id / 176, SM);
  } else {
    const int id = bid - MG_GUR_BLKS - MG_GUS_BLKS - MG_TWD_BLKS;
    transp_tile_body<128>(wsd, WSDT, IS_DIM, H_DIM, id % 16, id / 16, 0, SM);
  }
}

// ---------------- down GEMM core: BM=64, BN=128, single-buffer gload_lds, atomic ----------------
__device__ __forceinline__ void down_core_atomic(
    const u16* __restrict__ Ap, int astride,
    const u16* __restrict__ Bp, int bstride,
    int NT, int M, int m0, int n0, const int* tokS, float* __restrict__ outp) {
  __shared__ __align__(16) u16 S[12288]; // As 4096, Bs 8192
  const int tid = threadIdx.x;
  const int w = tid >> 6, l = tid & 63;
  const int r8 = l >> 3;
  const int sk = ((l & 7) ^ r8) * 8;

  size_t arow[2];
#pragma unroll
  for (int j = 0; j < 2; ++j) {
    const int m = w * 16 + j * 8 + r8;
    arow[j] = (size_t)(m0 + m < M ? m : (M - 1 - m0 > 0 ? M - 1 - m0 : 0)) * astride + sk;
  }
  size_t brow[4];
#pragma unroll
  for (int j = 0; j < 4; ++j)
    brow[j] = (size_t)(w * 32 + j * 8 + r8) * bstride + sk;

  const int fr = l & 15, fg = l >> 4;
  const f32x4 zero = {0.f, 0.f, 0.f, 0.f};
  f32x4 acc[4][2];
#pragma unroll
  for (int i = 0; i < 4; ++i)
#pragma unroll
    for (int j = 0; j < 2; ++j) acc[i][j] = zero;

  for (int kt = 0; kt < NT; ++kt) {
    const int k0 = kt * 64;
#pragma unroll
    for (int j = 0; j < 2; ++j)
      gload16(Ap + arow[j] + k0, S + (w * 2 + j) * 512);
#pragma unroll
    for (int j = 0; j < 4; ++j)
      gload16(Bp + brow[j] + k0, S + 4096 + (w * 4 + j) * 512);
    __syncthreads();
    const u16* AsC = S;
    const u16* BsC = S + 4096;
#pragma unroll
    for (int kk = 0; kk < 2; ++kk) {
      const int kb = kk * 64 + fg * 16;
      bf16x8 af[4], bfr[2];
#pragma unroll
      for (int mi = 0; mi < 4; ++mi)
        af[mi] = *(const bf16x8*)lds_sw(AsC, mi * 16 + fr, kb);
#pragma unroll
      for (int ni = 0; ni < 2; ++ni)
        bfr[ni] = *(const bf16x8*)lds_sw(BsC, w * 32 + ni * 16 + fr, kb);
#pragma unroll
      for (int mi = 0; mi < 4; ++mi)
#pragma unroll
        for (int ni = 0; ni < 2; ++ni) acc[mi][ni] = MFMA(af[mi], bfr[ni], acc[mi][ni]);
    }
    __syncthreads();
  }

#pragma unroll
  for (int mi = 0; mi < 4; ++mi) {
#pragma unroll
    for (int r = 0; r < 4; ++r) {
      const int ml = mi * 16 + fg * 4 + r;
      if (m0 + ml >= M) continue;
      float* op = outp + (size_t)tokS[ml] * H_DIM + n0 + w * 32;
#pragma unroll
      for (int ni = 0; ni < 2; ++ni)
        atomicAdd(op + ni * 16 + fr, acc[mi][ni][r]);
    }
  }
}

// single down launch: z=0..15 routed experts, z=16 shared; all atomic into
// the pre-zeroed output (zeroed by fused_pre_k; same-stream ordering).
__global__ __launch_bounds__(256, 4) void down_all_k(
    const u16* __restrict__ ACTC, const u16* __restrict__ WDT,
    const u16* __restrict__ ACTS, const u16* __restrict__ WSDT,
    const int* __restrict__ cnt, const int* __restrict__ tok,
    float* __restrict__ outp) {
  const int e = blockIdx.z;
  const bool shared = (e == E_NUM);
  const int M = shared ? T_TOK : cnt[e];
  const int m0 = blockIdx.y * 64;
  if (m0 >= M) return;
  const int n0 = blockIdx.x * 128;
  __shared__ int tokS[64];
  const int tid = threadIdx.x;
  if (tid < 64) {
    const int m = m0 + tid;
    tokS[tid] = shared ? m : tok[e * T_TOK + (m < M ? m : M - 1)];
  }
  __syncthreads();
  if (shared)
    down_core_atomic(ACTS + (size_t)m0 * IS_DIM, IS_DIM,
                     WSDT + (size_t)n0 * IS_DIM, IS_DIM,
                     IS_DIM / 64, M, m0, n0, tokS, outp);
  else
    down_core_atomic(ACTC + ((size_t)e * T_TOK + m0) * I_DIM, I_DIM,
                     WDT + ((size_t)e * H_DIM + n0) * I_DIM, I_DIM,
                     I_DIM / 64, M, m0, n0, tokS, outp);
}

extern "C" void kernel_launch(void* const* d_in, const int* in_sizes, int n_in,
                              void* d_out, int out_size, void* d_ws, size_t ws_size,
                              hipStream_t stream) {
  const float* x    = (const float*)d_in[0];
  const float* wg   = (const float*)d_in[1];
  const float* wgu  = (const float*)d_in[2];
  const float* wd   = (const float*)d_in[3];
  const float* wsgu = (const float*)d_in[4];
  const float* wsd  = (const float*)d_in[5];
  float* out = (float*)d_out;

  char* ws = (char*)d_ws;
  size_t off = 0;
  auto alloc = [&](size_t b) { size_t r = off; off += (b + 255) & ~(size_t)255; return r; };
  u16*   XB    = (u16*)  (ws + alloc((size_t)T_TOK * H_DIM * 2));
  float* COMB  = (float*)(ws + alloc((size_t)T_TOK * E_NUM * 4));
  int*   CNT   = (int*)  (ws + alloc((size_t)E_NUM * 4));
  int*   TOK   = (int*)  (ws + alloc((size_t)E_NUM * T_TOK * 4));
  u16*   WGUT  = (u16*)  (ws + alloc((size_t)E_NUM * 2 * I_DIM * H_DIM * 2)); // [e][1408][2048]
  u16*   WDT   = (u16*)  (ws + alloc((size_t)E_NUM * H_DIM * I_DIM * 2));     // [e][2048][704]
  u16*   WSGUT = (u16*)  (ws + alloc((size_t)2 * IS_DIM * H_DIM * 2));        // [2816][2048]
  u16*   WSDT  = (u16*)  (ws + alloc((size_t)H_DIM * IS_DIM * 2));            // [2048][1408]
  u16*   ACTC  = (u16*)  (ws + alloc((size_t)E_NUM * T_TOK * I_DIM * 2));     // [e][1024][704]
  u16*   ACTS  = (u16*)  (ws + alloc((size_t)T_TOK * IS_DIM * 2));            // [1024][1408]
  if (ws_size < off) return;

  // fused pre-pass: router (+x->bf16) + out-zero + wgu/wsgu transposes
  fused_pre_k<<<FP_ROUTER + FP_ZERO + FP_WGU + FP_WSGU, 256, 0, stream>>>(
      x, wg, COMB, XB, wgu, wsgu, WGUT, WSGUT, out);
  dispatch_k<<<E_NUM, 256, 0, stream>>>(COMB, CNT, TOK);
  // mega: routed gu + shared gu GEMMs first, wd/wsd transposes fill behind
  mega_k<<<MG_GUR_BLKS + MG_GUS_BLKS + MG_TWD_BLKS + MG_TWSD_BLKS, 256, 0, stream>>>(
      XB, WGUT, WSGUT, COMB, CNT, TOK, ACTC, ACTS, wd, wsd, WDT, WSDT);
  // single all-atomic down pass (routed z=0..15, shared z=16) into zeroed out
  down_all_k<<<dim3(H_DIM / 128, T_TOK / 64, E_NUM + 1), 256, 0, stream>>>(
      ACTC, WDT, ACTS, WSDT, CNT, TOK, out);
}

// Round 16
// 251.009 us; speedup vs baseline: 1.0012x; 1.0012x over previous
//
#include <hip/hip_runtime.h>

typedef unsigned short u16;
typedef u16 u16x8 __attribute__((ext_vector_type(8)));
typedef __bf16 bf16x8 __attribute__((ext_vector_type(8)));
typedef float f32x4 __attribute__((ext_vector_type(4)));
typedef unsigned u32x2 __attribute__((ext_vector_type(2)));

#define T_TOK 1024
#define H_DIM 2048
#define E_NUM 16
#define I_DIM 704
#define IS_DIM 1408

#define MFMA(a, b, c) __builtin_amdgcn_mfma_f32_16x16x32_bf16(a, b, c, 0, 0, 0)

__device__ __forceinline__ u16 f2bf(float f) {
  union { float f; unsigned u; } v; v.f = f;
  unsigned r = v.u + 0x7fffu + ((v.u >> 16) & 1u);
  return (u16)(r >> 16);
}

// async global->LDS 16B per lane; dest linear (wave-uniform base + lane*16)
__device__ __forceinline__ void gload16(const void* g, void* l) {
  __builtin_amdgcn_global_load_lds(
      (const __attribute__((address_space(1))) unsigned int*)g,
      (__attribute__((address_space(3))) unsigned int*)l, 16, 0, 0);
}

// Swizzled LDS read address within 128-byte rows: XOR bits[6:4] with (row&7).
__device__ __forceinline__ const char* lds_sw(const u16* base, int row, int kByte) {
  return (const char*)base + row * 128 + (kByte ^ ((row & 7) << 4));
}

// ---------------- transpose+convert tile body: [R][C] f32 -> [C][R] bf16 ----------------
// TR rows x 128 cols per block. ALL 2*TR/16 f32x4 loads are hoisted into a
// statically-indexed register array BEFORE the pack loop: with a 2-block/CU
// VGPR budget (128) this keeps ~16 loads in flight per thread (latency fix —
// r14/r15 serialized load->pack chains at ~4 in flight = 2 TB/s).
template <int TR>
__device__ __forceinline__ void transp_tile_body(const float* __restrict__ in,
                                                 u16* __restrict__ outp, int R, int C,
                                                 int cx, int ry, int z, char* SM) {
  unsigned (*tile)[130] = (unsigned(*)[130])SM;
  const size_t base = (size_t)z * (size_t)R * C;
  const int c0 = cx * 128, r0 = ry * TR;
  const int tid = threadIdx.x;
  const int rp0 = tid >> 5, cc = tid & 31;
  f32x4 v[2 * (TR / 16)];
#pragma unroll
  for (int j = 0; j < TR / 16; ++j) {
    const int rp = j * 8 + rp0;
    const float* p0 = in + base + (size_t)(r0 + 2 * rp) * C + c0 + cc * 4;
    v[2 * j] = *(const f32x4*)(p0);
    v[2 * j + 1] = *(const f32x4*)(p0 + C);
  }
#pragma unroll
  for (int j = 0; j < TR / 16; ++j) {
    const int rp = j * 8 + rp0;
    u32x2 wa, wb;
    wa[0] = (unsigned)f2bf(v[2 * j][0]) | ((unsigned)f2bf(v[2 * j + 1][0]) << 16);
    wa[1] = (unsigned)f2bf(v[2 * j][1]) | ((unsigned)f2bf(v[2 * j + 1][1]) << 16);
    wb[0] = (unsigned)f2bf(v[2 * j][2]) | ((unsigned)f2bf(v[2 * j + 1][2]) << 16);
    wb[1] = (unsigned)f2bf(v[2 * j][3]) | ((unsigned)f2bf(v[2 * j + 1][3]) << 16);
    *(u32x2*)&tile[rp][cc * 4] = wa;
    *(u32x2*)&tile[rp][cc * 4 + 2] = wb;
  }
  __syncthreads();
#pragma unroll
  for (int i = 0; i < TR / 4; ++i) {
    const int idx = i * 256 + tid;
    const int oc = idx / (TR / 2), pr = idx % (TR / 2);
    *(unsigned*)&outp[base + (size_t)(c0 + oc) * R + r0 + 2 * pr] = tile[pr][oc];
  }
}

// ---------------- router body (one block per token) + x->bf16 convert ----------------
__device__ __forceinline__ void router_body(const float* __restrict__ x,
                                            const float* __restrict__ wg,
                                            float* __restrict__ comb,
                                            u16* __restrict__ XB, int t, char* SM) {
  const int tid = threadIdx.x;
  const float* xr = x + (size_t)t * H_DIM;
  const int h0 = tid * 8;
  f32x4 a = *(const f32x4*)(xr + h0);
  f32x4 b = *(const f32x4*)(xr + h0 + 4);
  u16x8 o;
  o[0] = f2bf(a[0]); o[1] = f2bf(a[1]); o[2] = f2bf(a[2]); o[3] = f2bf(a[3]);
  o[4] = f2bf(b[0]); o[5] = f2bf(b[1]); o[6] = f2bf(b[2]); o[7] = f2bf(b[3]);
  *(u16x8*)(XB + (size_t)t * H_DIM + h0) = o;

  float acc[E_NUM];
#pragma unroll
  for (int e = 0; e < E_NUM; ++e) acc[e] = 0.f;
#pragma unroll
  for (int j = 0; j < 8; ++j) {
    const float xv = j < 4 ? a[j] : b[j - 4];
    const f32x4* wr = (const f32x4*)(wg + (size_t)(h0 + j) * E_NUM);
#pragma unroll
    for (int q = 0; q < 4; ++q) {
      f32x4 w4 = wr[q];
      acc[q * 4 + 0] += xv * w4[0];
      acc[q * 4 + 1] += xv * w4[1];
      acc[q * 4 + 2] += xv * w4[2];
      acc[q * 4 + 3] += xv * w4[3];
    }
  }
#pragma unroll
  for (int e = 0; e < E_NUM; ++e)
    for (int off = 32; off > 0; off >>= 1) acc[e] += __shfl_down(acc[e], off);
  float (*part)[E_NUM] = (float(*)[E_NUM])SM;
  if ((tid & 63) == 0) {
#pragma unroll
    for (int e = 0; e < E_NUM; ++e) part[tid >> 6][e] = acc[e];
  }
  __syncthreads();
  if (tid == 0) {
    float p[E_NUM];
    float mx = -1e30f;
    for (int e = 0; e < E_NUM; ++e) {
      p[e] = part[0][e] + part[1][e] + part[2][e] + part[3][e];
      mx = fmaxf(mx, p[e]);
    }
    float s = 0.f;
    for (int e = 0; e < E_NUM; ++e) { p[e] = __expf(p[e] - mx); s += p[e]; }
    const float invs = 1.f / s;
    for (int e = 0; e < E_NUM; ++e) p[e] *= invs;
    float gs[4];
    for (int g = 0; g < 4; ++g)
      gs[g] = fmaxf(fmaxf(p[4 * g], p[4 * g + 1]), fmaxf(p[4 * g + 2], p[4 * g + 3]));
    int g1 = 0;
    for (int g = 1; g < 4; ++g) if (gs[g] > gs[g1]) g1 = g;
    int g2 = -1;
    for (int g = 0; g < 4; ++g) {
      if (g == g1) continue;
      if (g2 < 0 || gs[g] > gs[g2]) g2 = g;
    }
    float m2[E_NUM], cw[E_NUM];
    for (int e = 0; e < E_NUM; ++e) {
      int g = e >> 2;
      m2[e] = (g == g1 || g == g2) ? p[e] : 0.f;
      cw[e] = 0.f;
    }
    float sum6 = 0.f;
    for (int k = 0; k < 6; ++k) {
      int bi = 0; float bv = -1.f;
      for (int e = 0; e < E_NUM; ++e)
        if (m2[e] > bv) { bv = m2[e]; bi = e; }
      cw[bi] = bv; sum6 += bv; m2[bi] = -2.f;
    }
    const float scale = 2.5f / sum6;
    for (int e = 0; e < E_NUM; ++e) comb[t * E_NUM + e] = cw[e] * scale;
  }
}

// ---------------- fused pre-pass: router + out-zero + wgu/wsgu transposes ----------------
// __launch_bounds__(256,2): 128-VGPR budget so the transpose's 16 loads stay
// in flight (131 KB/CU in-flight >> ~30 KB needed for BW-bound).
#define FP_ROUTER T_TOK                 /* 1024 */
#define FP_ZERO 512                     /* 8.4MB out zero */
#define FP_WGU (11 * 16 * 16)           /* 2816: wgu 128x128 tiles */
#define FP_WSGU (22 * 16)               /* 352:  wsgu 128x128 tiles */
__global__ __launch_bounds__(256, 2) void fused_pre_k(
    const float* __restrict__ x, const float* __restrict__ wg,
    float* __restrict__ comb, u16* __restrict__ XB,
    const float* __restrict__ wgu, const float* __restrict__ wsgu,
    u16* __restrict__ WGUT, u16* __restrict__ WSGUT, float* __restrict__ outz) {
  __shared__ __align__(16) char SM[33280];
  const int bid = blockIdx.x;
  if (bid < FP_ROUTER) {
    router_body(x, wg, comb, XB, bid, SM);
  } else if (bid < FP_ROUTER + FP_ZERO) {
    const int i = ((bid - FP_ROUTER) * 256 + threadIdx.x) * 16;
    const f32x4 z = {0.f, 0.f, 0.f, 0.f};
#pragma unroll
    for (int j = 0; j < 4; ++j) *(f32x4*)(outz + i + j * 4) = z;
  } else if (bid < FP_ROUTER + FP_ZERO + FP_WGU) {
    const int id = bid - FP_ROUTER - FP_ZERO;
    transp_tile_body<128>(wgu, WGUT, H_DIM, 2 * I_DIM, id % 11, (id / 11) % 16,
                          id / 176, SM);
  } else {
    const int id = bid - FP_ROUTER - FP_ZERO - FP_WGU;
    transp_tile_body<128>(wsgu, WSGUT, H_DIM, 2 * IS_DIM, id % 22, id / 22, 0, SM);
  }
}

// ---------------- dispatch: per-expert ordered token lists (no atomics) ----------------
__global__ __launch_bounds__(256) void dispatch_k(const float* __restrict__ comb,
                                                  int* __restrict__ cnt,
                                                  int* __restrict__ tok) {
  const int e = blockIdx.x;
  const int tid = threadIdx.x;
  const int lane = tid & 63, wid = tid >> 6;
  __shared__ int wtot[4];
  int running = 0;
  for (int chunk = 0; chunk < T_TOK / 256; ++chunk) {
    const int t = chunk * 256 + tid;
    const bool sel = comb[t * E_NUM + e] > 0.f;
    unsigned long long mask = __ballot(sel);
    const int pre = __popcll(mask & ((1ull << lane) - 1ull));
    if (lane == 0) wtot[wid] = __popcll(mask);
    __syncthreads();
    int wbase = running;
    for (int w = 0; w < wid; ++w) wbase += wtot[w];
    if (sel) tok[e * T_TOK + wbase + pre] = t;
    running += wtot[0] + wtot[1] + wtot[2] + wtot[3];
    __syncthreads();
  }
  if (tid == 0) cnt[e] = running;
}

// ---------------- fused gate/up GEMM body (m97 structure; 32KB LDS) ----------------
__device__ __forceinline__ void gu_body(
    const u16* __restrict__ A, const u16* __restrict__ Bt,
    const float* __restrict__ comb, const int* __restrict__ cnt,
    const int* __restrict__ tok, u16* __restrict__ outp,
    int gu_off, long long bt_e_stride, long long out_e_stride, int out_stride,
    int bx, int by, int e, char* SM) {
  const int M = cnt ? cnt[e] : T_TOK;
  const int m0 = by * 128;
  if (m0 >= M) return;
  u16* S = (u16*)SM; // As 8192, Bg 4096, Bu 4096 (u16 counts) = 32768 B

  const int n0 = bx * 64;
  const u16* Bte = Bt + (size_t)e * bt_e_stride;
  const u16* Bgp = Bte + (size_t)n0 * H_DIM;
  const u16* Bup = Bte + (size_t)(gu_off + n0) * H_DIM;
  const int tid = threadIdx.x;
  const int w = tid >> 6, l = tid & 63;
  const int r8 = l >> 3;
  const int sk = ((l & 7) ^ r8) * 8; // inverse-swizzled source k offset (elems)

  size_t arow[4];
#pragma unroll
  for (int j = 0; j < 4; ++j) {
    const int m = m0 + w * 32 + j * 8 + r8;
    const int mc = m < M ? m : M - 1;
    const int t = tok ? tok[e * T_TOK + mc] : mc;
    arow[j] = (size_t)t * H_DIM + sk;
  }

  const int wr = tid >> 7;
  const int wc = (tid >> 6) & 1;
  const int fr = l & 15;
  const int fg = l >> 4;

  const f32x4 zero = {0.f, 0.f, 0.f, 0.f};
  f32x4 accg[4][2], accu[4][2];
#pragma unroll
  for (int i = 0; i < 4; ++i)
#pragma unroll
    for (int j = 0; j < 2; ++j) { accg[i][j] = zero; accu[i][j] = zero; }

  for (int kt = 0; kt < H_DIM / 64; ++kt) {
    const int k0 = kt * 64;
#pragma unroll
    for (int j = 0; j < 4; ++j)
      gload16(A + arow[j] + k0, S + (w * 4 + j) * 512);
#pragma unroll
    for (int j = 0; j < 2; ++j) {
      const size_t br = (size_t)(w * 16 + j * 8 + r8) * H_DIM + sk + k0;
      gload16(Bgp + br, S + 8192 + (w * 2 + j) * 512);
      gload16(Bup + br, S + 12288 + (w * 2 + j) * 512);
    }
    __syncthreads();
    const u16* AsC = S;
    const u16* BgC = S + 8192;
    const u16* BuC = S + 12288;
#pragma unroll
    for (int kk = 0; kk < 2; ++kk) {
      const int kb = kk * 64 + fg * 16;
      bf16x8 af[4], bg[2], bu[2];
#pragma unroll
      for (int mi = 0; mi < 4; ++mi)
        af[mi] = *(const bf16x8*)lds_sw(AsC, wr * 64 + mi * 16 + fr, kb);
#pragma unroll
      for (int ni = 0; ni < 2; ++ni) {
        bg[ni] = *(const bf16x8*)lds_sw(BgC, wc * 32 + ni * 16 + fr, kb);
        bu[ni] = *(const bf16x8*)lds_sw(BuC, wc * 32 + ni * 16 + fr, kb);
      }
#pragma unroll
      for (int mi = 0; mi < 4; ++mi)
#pragma unroll
        for (int ni = 0; ni < 2; ++ni) {
          accg[mi][ni] = MFMA(af[mi], bg[ni], accg[mi][ni]);
          accu[mi][ni] = MFMA(af[mi], bu[ni], accu[mi][ni]);
        }
    }
    __syncthreads();
  }

  const int colb = n0 + wc * 32;
#pragma unroll
  for (int mi = 0; mi < 4; ++mi) {
#pragma unroll
    for (int r = 0; r < 4; ++r) {
      const int ml = wr * 64 + mi * 16 + fg * 4 + r;
      if (m0 + ml >= M) continue;
      const int trow = tok ? tok[e * T_TOK + m0 + ml] : (m0 + ml);
      const float wgt = comb ? comb[trow * E_NUM + e] : 1.0f;
      const size_t rowoff = (size_t)e * out_e_stride + (size_t)(m0 + ml) * out_stride;
#pragma unroll
      for (int ni = 0; ni < 2; ++ni) {
        float g = accg[mi][ni][r];
        float u = accu[mi][ni][r];
        float sg = g / (1.f + __expf(-g));
        outp[rowoff + colb + ni * 16 + fr] = f2bf(sg * u * wgt);
      }
    }
  }
}

// ---------------- mega kernel: gu_routed + gu_shared + transp(wd) + transp(wsd) ----------------
// Sequential block order (GEMM ids first): GEMM blocks pack CUs densely at the
// start (cross-block wave overlap), transposes fill behind. Do NOT interleave.
#define MG_GUR_BLKS (11 * 8 * 16) /* 1408 */
#define MG_GUS_BLKS (22 * 8)      /* 176  */
#define MG_TWD_BLKS (16 * 11 * 16)/* 2816: wd 64x128 tiles */
#define MG_TWSD_BLKS (16 * 11)    /* 176:  wsd 128x128 tiles */
__global__ __launch_bounds__(256, 4) void mega_k(
    const u16* __restrict__ XB, const u16* __restrict__ WGUT,
    const u16* __restrict__ WSGUT, const float* __restrict__ comb,
    const int* __restrict__ cnt, const int* __restrict__ tok,
    u16* __restrict__ ACTC, u16* __restrict__ ACTS,
    const float* __restrict__ wd, const float* __restrict__ wsd,
    u16* __restrict__ WDT, u16* __restrict__ WSDT) {
  __shared__ __align__(16) char SM[33280];
  const int bid = blockIdx.x;
  if (bid < MG_GUR_BLKS) {
    gu_body(XB, WGUT, comb, cnt, tok, ACTC, I_DIM, (long long)(2 * I_DIM) * H_DIM,
            (long long)T_TOK * I_DIM, I_DIM, bid % 11, (bid / 11) % 8, bid / 88, SM);
  } else if (bid < MG_GUR_BLKS + MG_GUS_BLKS) {
    const int id = bid - MG_GUR_BLKS;
    gu_body(XB, WSGUT, nullptr, nullptr, nullptr, ACTS, IS_DIM, 0, 0, IS_DIM,
            id % 22, id / 22, 0, SM);
  } else if (bid < MG_GUR_BLKS + MG_GUS_BLKS + MG_TWD_BLKS) {
    const int id = bid - MG_GUR_BLKS - MG_GUS_BLKS;
    transp_tile_body<64>(wd, WDT, I_DIM, H_DIM, id % 16, (id / 16) % 11,
                         id / 176, SM);
  } else {
    const int id = bid - MG_GUR_BLKS - MG_GUS_BLKS - MG_TWD_BLKS;
    transp_tile_body<128>(wsd, WSDT, IS_DIM, H_DIM, id % 16, id / 16, 0, SM);
  }
}

// ---------------- down GEMM core: BM=64, BN=128, single-buffer gload_lds, atomic ----------------
__device__ __forceinline__ void down_core_atomic(
    const u16* __restrict__ Ap, int astride,
    const u16* __restrict__ Bp, int bstride,
    int NT, int M, int m0, int n0, const int* tokS, float* __restrict__ outp) {
  __shared__ __align__(16) u16 S[12288]; // As 4096, Bs 8192
  const int tid = threadIdx.x;
  const int w = tid >> 6, l = tid & 63;
  const int r8 = l >> 3;
  const int sk = ((l & 7) ^ r8) * 8;

  size_t arow[2];
#pragma unroll
  for (int j = 0; j < 2; ++j) {
    const int m = w * 16 + j * 8 + r8;
    arow[j] = (size_t)(m0 + m < M ? m : (M - 1 - m0 > 0 ? M - 1 - m0 : 0)) * astride + sk;
  }
  size_t brow[4];
#pragma unroll
  for (int j = 0; j < 4; ++j)
    brow[j] = (size_t)(w * 32 + j * 8 + r8) * bstride + sk;

  const int fr = l & 15, fg = l >> 4;
  const f32x4 zero = {0.f, 0.f, 0.f, 0.f};
  f32x4 acc[4][2];
#pragma unroll
  for (int i = 0; i < 4; ++i)
#pragma unroll
    for (int j = 0; j < 2; ++j) acc[i][j] = zero;

  for (int kt = 0; kt < NT; ++kt) {
    const int k0 = kt * 64;
#pragma unroll
    for (int j = 0; j < 2; ++j)
      gload16(Ap + arow[j] + k0, S + (w * 2 + j) * 512);
#pragma unroll
    for (int j = 0; j < 4; ++j)
      gload16(Bp + brow[j] + k0, S + 4096 + (w * 4 + j) * 512);
    __syncthreads();
    const u16* AsC = S;
    const u16* BsC = S + 4096;
#pragma unroll
    for (int kk = 0; kk < 2; ++kk) {
      const int kb = kk * 64 + fg * 16;
      bf16x8 af[4], bfr[2];
#pragma unroll
      for (int mi = 0; mi < 4; ++mi)
        af[mi] = *(const bf16x8*)lds_sw(AsC, mi * 16 + fr, kb);
#pragma unroll
      for (int ni = 0; ni < 2; ++ni)
        bfr[ni] = *(const bf16x8*)lds_sw(BsC, w * 32 + ni * 16 + fr, kb);
#pragma unroll
      for (int mi = 0; mi < 4; ++mi)
#pragma unroll
        for (int ni = 0; ni < 2; ++ni) acc[mi][ni] = MFMA(af[mi], bfr[ni], acc[mi][ni]);
    }
    __syncthreads();
  }

#pragma unroll
  for (int mi = 0; mi < 4; ++mi) {
#pragma unroll
    for (int r = 0; r < 4; ++r) {
      const int ml = mi * 16 + fg * 4 + r;
      if (m0 + ml >= M) continue;
      float* op = outp + (size_t)tokS[ml] * H_DIM + n0 + w * 32;
#pragma unroll
      for (int ni = 0; ni < 2; ++ni)
        atomicAdd(op + ni * 16 + fr, acc[mi][ni][r]);
    }
  }
}

// single down launch: z=0..15 routed experts, z=16 shared; all atomic into
// the pre-zeroed output (zeroed by fused_pre_k; same-stream ordering).
__global__ __launch_bounds__(256, 4) void down_all_k(
    const u16* __restrict__ ACTC, const u16* __restrict__ WDT,
    const u16* __restrict__ ACTS, const u16* __restrict__ WSDT,
    const int* __restrict__ cnt, const int* __restrict__ tok,
    float* __restrict__ outp) {
  const int e = blockIdx.z;
  const bool shared = (e == E_NUM);
  const int M = shared ? T_TOK : cnt[e];
  const int m0 = blockIdx.y * 64;
  if (m0 >= M) return;
  const int n0 = blockIdx.x * 128;
  __shared__ int tokS[64];
  const int tid = threadIdx.x;
  if (tid < 64) {
    const int m = m0 + tid;
    tokS[tid] = shared ? m : tok[e * T_TOK + (m < M ? m : M - 1)];
  }
  __syncthreads();
  if (shared)
    down_core_atomic(ACTS + (size_t)m0 * IS_DIM, IS_DIM,
                     WSDT + (size_t)n0 * IS_DIM, IS_DIM,
                     IS_DIM / 64, M, m0, n0, tokS, outp);
  else
    down_core_atomic(ACTC + ((size_t)e * T_TOK + m0) * I_DIM, I_DIM,
                     WDT + ((size_t)e * H_DIM + n0) * I_DIM, I_DIM,
                     I_DIM / 64, M, m0, n0, tokS, outp);
}

extern "C" void kernel_launch(void* const* d_in, const int* in_sizes, int n_in,
                              void* d_out, int out_size, void* d_ws, size_t ws_size,
                              hipStream_t stream) {
  const float* x    = (const float*)d_in[0];
  const float* wg   = (const float*)d_in[1];
  const float* wgu  = (const float*)d_in[2];
  const float* wd   = (const float*)d_in[3];
  const float* wsgu = (const float*)d_in[4];
  const float* wsd  = (const float*)d_in[5];
  float* out = (float*)d_out;

  char* ws = (char*)d_ws;
  size_t off = 0;
  auto alloc = [&](size_t b) { size_t r = off; off += (b + 255) & ~(size_t)255; return r; };
  u16*   XB    = (u16*)  (ws + alloc((size_t)T_TOK * H_DIM * 2));
  float* COMB  = (float*)(ws + alloc((size_t)T_TOK * E_NUM * 4));
  int*   CNT   = (int*)  (ws + alloc((size_t)E_NUM * 4));
  int*   TOK   = (int*)  (ws + alloc((size_t)E_NUM * T_TOK * 4));
  u16*   WGUT  = (u16*)  (ws + alloc((size_t)E_NUM * 2 * I_DIM * H_DIM * 2)); // [e][1408][2048]
  u16*   WDT   = (u16*)  (ws + alloc((size_t)E_NUM * H_DIM * I_DIM * 2));     // [e][2048][704]
  u16*   WSGUT = (u16*)  (ws + alloc((size_t)2 * IS_DIM * H_DIM * 2));        // [2816][2048]
  u16*   WSDT  = (u16*)  (ws + alloc((size_t)H_DIM * IS_DIM * 2));            // [2048][1408]
  u16*   ACTC  = (u16*)  (ws + alloc((size_t)E_NUM * T_TOK * I_DIM * 2));     // [e][1024][704]
  u16*   ACTS  = (u16*)  (ws + alloc((size_t)T_TOK * IS_DIM * 2));            // [1024][1408]
  if (ws_size < off) return;

  // fused pre-pass: router (+x->bf16) + out-zero + wgu/wsgu transposes
  fused_pre_k<<<FP_ROUTER + FP_ZERO + FP_WGU + FP_WSGU, 256, 0, stream>>>(
      x, wg, COMB, XB, wgu, wsgu, WGUT, WSGUT, out);
  dispatch_k<<<E_NUM, 256, 0, stream>>>(COMB, CNT, TOK);
  // mega: routed gu + shared gu GEMMs first, wd/wsd transposes fill behind
  mega_k<<<MG_GUR_BLKS + MG_GUS_BLKS + MG_TWD_BLKS + MG_TWSD_BLKS, 256, 0, stream>>>(
      XB, WGUT, WSGUT, COMB, CNT, TOK, ACTC, ACTS, wd, wsd, WDT, WSDT);
  // single all-atomic down pass (routed z=0..15, shared z=16) into zeroed out
  down_all_k<<<dim3(H_DIM / 128, T_TOK / 64, E_NUM + 1), 256, 0, stream>>>(
      ACTC, WDT, ACTS, WSDT, CNT, TOK, out);
}

// Round 17
// 249.265 us; speedup vs baseline: 1.0082x; 1.0070x over previous
//
#include <hip/hip_runtime.h>

typedef unsigned short u16;
typedef u16 u16x8 __attribute__((ext_vector_type(8)));
typedef __bf16 bf16x8 __attribute__((ext_vector_type(8)));
typedef float f32x4 __attribute__((ext_vector_type(4)));
typedef unsigned u32x2 __attribute__((ext_vector_type(2)));

#define T_TOK 1024
#define H_DIM 2048
#define E_NUM 16
#define I_DIM 704
#define IS_DIM 1408

#define MFMA(a, b, c) __builtin_amdgcn_mfma_f32_16x16x32_bf16(a, b, c, 0, 0, 0)

__device__ __forceinline__ u16 f2bf(float f) {
  union { float f; unsigned u; } v; v.f = f;
  unsigned r = v.u + 0x7fffu + ((v.u >> 16) & 1u);
  return (u16)(r >> 16);
}

// async global->LDS 16B per lane; dest wave-uniform base + lane*16
__device__ __forceinline__ void gload16(const void* g, void* l) {
  __builtin_amdgcn_global_load_lds(
      (const __attribute__((address_space(1))) unsigned int*)g,
      (__attribute__((address_space(3))) unsigned int*)l, 16, 0, 0);
}

// Swizzled LDS read address within 128-byte rows: XOR bits[6:4] with (row&7).
__device__ __forceinline__ const char* lds_sw(const u16* base, int row, int kByte) {
  return (const char*)base + row * 128 + (kByte ^ ((row & 7) << 4));
}

// ---------------- transpose+convert via global_load_lds: [R][C] f32 -> [C][R] bf16 ----
// 64 rows x 128 cols per block (32 KB LDS). Staging is fire-and-forget
// (gload16, no VGPR dep chain -> fixes the r14-r16 ~2 TB/s latency wall where
// hipcc kept only ~4 reg-loads in flight). LDS is 16B-chunk swizzled
// (c' = c ^ (row&31)) via the per-lane GLOBAL source address; pack reads
// mirror the swizzle -> column reads are <=8-way instead of 32-way conflicts.
__device__ __forceinline__ void transp_g_body(const float* __restrict__ in,
                                              u16* __restrict__ outp, int R, int C,
                                              int cx, int ry, int z, char* SM) {
  const size_t base = (size_t)z * (size_t)R * C;
  const int c0 = cx * 128, r0 = ry * 64;
  const int tid = threadIdx.x;
  const int w = tid >> 6;
#pragma unroll
  for (int j = 0; j < 8; ++j) {
    const int d = j * 256 + tid;          // 16B-chunk index, linear LDS order
    const int row = d >> 5, cp = d & 31;  // 32 chunks per 512B row
    const int c = cp ^ (row & 31);        // inverse-swizzled source chunk
    gload16(in + base + (size_t)(r0 + row) * C + c0 + c * 4,
            SM + (size_t)(j * 256 + w * 64) * 16);
  }
  __syncthreads();
#pragma unroll
  for (int i = 0; i < 8; ++i) {
    const int idx = i * 256 + tid;
    const int oc = idx >> 4, pp = idx & 15; // output col, row-quad
    float f[4];
#pragma unroll
    for (int k = 0; k < 4; ++k) {
      const int r = 4 * pp + k;
      f[k] = *(const float*)(SM + r * 512 + ((((oc >> 2) ^ (r & 31)) << 4)) +
                             (oc & 3) * 4);
    }
    u32x2 wv;
    wv[0] = (unsigned)f2bf(f[0]) | ((unsigned)f2bf(f[1]) << 16);
    wv[1] = (unsigned)f2bf(f[2]) | ((unsigned)f2bf(f[3]) << 16);
    *(u32x2*)&outp[base + (size_t)(c0 + oc) * R + r0 + 4 * pp] = wv;
  }
}

// ---------------- router body (one block per token) + x->bf16 convert ----------------
__device__ __forceinline__ void router_body(const float* __restrict__ x,
                                            const float* __restrict__ wg,
                                            float* __restrict__ comb,
                                            u16* __restrict__ XB, int t, char* SM) {
  const int tid = threadIdx.x;
  const float* xr = x + (size_t)t * H_DIM;
  const int h0 = tid * 8;
  f32x4 a = *(const f32x4*)(xr + h0);
  f32x4 b = *(const f32x4*)(xr + h0 + 4);
  u16x8 o;
  o[0] = f2bf(a[0]); o[1] = f2bf(a[1]); o[2] = f2bf(a[2]); o[3] = f2bf(a[3]);
  o[4] = f2bf(b[0]); o[5] = f2bf(b[1]); o[6] = f2bf(b[2]); o[7] = f2bf(b[3]);
  *(u16x8*)(XB + (size_t)t * H_DIM + h0) = o;

  float acc[E_NUM];
#pragma unroll
  for (int e = 0; e < E_NUM; ++e) acc[e] = 0.f;
#pragma unroll
  for (int j = 0; j < 8; ++j) {
    const float xv = j < 4 ? a[j] : b[j - 4];
    const f32x4* wr = (const f32x4*)(wg + (size_t)(h0 + j) * E_NUM);
#pragma unroll
    for (int q = 0; q < 4; ++q) {
      f32x4 w4 = wr[q];
      acc[q * 4 + 0] += xv * w4[0];
      acc[q * 4 + 1] += xv * w4[1];
      acc[q * 4 + 2] += xv * w4[2];
      acc[q * 4 + 3] += xv * w4[3];
    }
  }
#pragma unroll
  for (int e = 0; e < E_NUM; ++e)
    for (int off = 32; off > 0; off >>= 1) acc[e] += __shfl_down(acc[e], off);
  float (*part)[E_NUM] = (float(*)[E_NUM])SM;
  if ((tid & 63) == 0) {
#pragma unroll
    for (int e = 0; e < E_NUM; ++e) part[tid >> 6][e] = acc[e];
  }
  __syncthreads();
  if (tid == 0) {
    float p[E_NUM];
    float mx = -1e30f;
    for (int e = 0; e < E_NUM; ++e) {
      p[e] = part[0][e] + part[1][e] + part[2][e] + part[3][e];
      mx = fmaxf(mx, p[e]);
    }
    float s = 0.f;
    for (int e = 0; e < E_NUM; ++e) { p[e] = __expf(p[e] - mx); s += p[e]; }
    const float invs = 1.f / s;
    for (int e = 0; e < E_NUM; ++e) p[e] *= invs;
    float gs[4];
    for (int g = 0; g < 4; ++g)
      gs[g] = fmaxf(fmaxf(p[4 * g], p[4 * g + 1]), fmaxf(p[4 * g + 2], p[4 * g + 3]));
    int g1 = 0;
    for (int g = 1; g < 4; ++g) if (gs[g] > gs[g1]) g1 = g;
    int g2 = -1;
    for (int g = 0; g < 4; ++g) {
      if (g == g1) continue;
      if (g2 < 0 || gs[g] > gs[g2]) g2 = g;
    }
    float m2[E_NUM], cw[E_NUM];
    for (int e = 0; e < E_NUM; ++e) {
      int g = e >> 2;
      m2[e] = (g == g1 || g == g2) ? p[e] : 0.f;
      cw[e] = 0.f;
    }
    float sum6 = 0.f;
    for (int k = 0; k < 6; ++k) {
      int bi = 0; float bv = -1.f;
      for (int e = 0; e < E_NUM; ++e)
        if (m2[e] > bv) { bv = m2[e]; bi = e; }
      cw[bi] = bv; sum6 += bv; m2[bi] = -2.f;
    }
    const float scale = 2.5f / sum6;
    for (int e = 0; e < E_NUM; ++e) comb[t * E_NUM + e] = cw[e] * scale;
  }
}

// ---------------- fused pre-pass: router + out-zero + wgu/wsgu transposes ----------------
#define FP_ROUTER T_TOK                 /* 1024 */
#define FP_ZERO 512                     /* 8.4MB out zero */
#define FP_WGU (11 * 32 * 16)           /* 5632: wgu 64x128 tiles */
#define FP_WSGU (22 * 32)               /* 704:  wsgu 64x128 tiles */
__global__ __launch_bounds__(256) void fused_pre_k(
    const float* __restrict__ x, const float* __restrict__ wg,
    float* __restrict__ comb, u16* __restrict__ XB,
    const float* __restrict__ wgu, const float* __restrict__ wsgu,
    u16* __restrict__ WGUT, u16* __restrict__ WSGUT, float* __restrict__ outz) {
  __shared__ __align__(16) char SM[32768];
  const int bid = blockIdx.x;
  if (bid < FP_ROUTER) {
    router_body(x, wg, comb, XB, bid, SM);
  } else if (bid < FP_ROUTER + FP_ZERO) {
    const int i = ((bid - FP_ROUTER) * 256 + threadIdx.x) * 16;
    const f32x4 z = {0.f, 0.f, 0.f, 0.f};
#pragma unroll
    for (int j = 0; j < 4; ++j) *(f32x4*)(outz + i + j * 4) = z;
  } else if (bid < FP_ROUTER + FP_ZERO + FP_WGU) {
    const int id = bid - FP_ROUTER - FP_ZERO;
    transp_g_body(wgu, WGUT, H_DIM, 2 * I_DIM, id % 11, (id / 11) % 32,
                  id / 352, SM);
  } else {
    const int id = bid - FP_ROUTER - FP_ZERO - FP_WGU;
    transp_g_body(wsgu, WSGUT, H_DIM, 2 * IS_DIM, id % 22, id / 22, 0, SM);
  }
}

// ---------------- dispatch: per-expert ordered token lists (no atomics) ----------------
__global__ __launch_bounds__(256) void dispatch_k(const float* __restrict__ comb,
                                                  int* __restrict__ cnt,
                                                  int* __restrict__ tok) {
  const int e = blockIdx.x;
  const int tid = threadIdx.x;
  const int lane = tid & 63, wid = tid >> 6;
  __shared__ int wtot[4];
  int running = 0;
  for (int chunk = 0; chunk < T_TOK / 256; ++chunk) {
    const int t = chunk * 256 + tid;
    const bool sel = comb[t * E_NUM + e] > 0.f;
    unsigned long long mask = __ballot(sel);
    const int pre = __popcll(mask & ((1ull << lane) - 1ull));
    if (lane == 0) wtot[wid] = __popcll(mask);
    __syncthreads();
    int wbase = running;
    for (int w = 0; w < wid; ++w) wbase += wtot[w];
    if (sel) tok[e * T_TOK + wbase + pre] = t;
    running += wtot[0] + wtot[1] + wtot[2] + wtot[3];
    __syncthreads();
  }
  if (tid == 0) cnt[e] = running;
}

// ---------------- fused gate/up GEMM body (m97 structure; 32KB LDS) ----------------
__device__ __forceinline__ void gu_body(
    const u16* __restrict__ A, const u16* __restrict__ Bt,
    const float* __restrict__ comb, const int* __restrict__ cnt,
    const int* __restrict__ tok, u16* __restrict__ outp,
    int gu_off, long long bt_e_stride, long long out_e_stride, int out_stride,
    int bx, int by, int e, char* SM) {
  const int M = cnt ? cnt[e] : T_TOK;
  const int m0 = by * 128;
  if (m0 >= M) return;
  u16* S = (u16*)SM; // As 8192, Bg 4096, Bu 4096 (u16 counts) = 32768 B

  const int n0 = bx * 64;
  const u16* Bte = Bt + (size_t)e * bt_e_stride;
  const u16* Bgp = Bte + (size_t)n0 * H_DIM;
  const u16* Bup = Bte + (size_t)(gu_off + n0) * H_DIM;
  const int tid = threadIdx.x;
  const int w = tid >> 6, l = tid & 63;
  const int r8 = l >> 3;
  const int sk = ((l & 7) ^ r8) * 8; // inverse-swizzled source k offset (elems)

  size_t arow[4];
#pragma unroll
  for (int j = 0; j < 4; ++j) {
    const int m = m0 + w * 32 + j * 8 + r8;
    const int mc = m < M ? m : M - 1;
    const int t = tok ? tok[e * T_TOK + mc] : mc;
    arow[j] = (size_t)t * H_DIM + sk;
  }

  const int wr = tid >> 7;
  const int wc = (tid >> 6) & 1;
  const int fr = l & 15;
  const int fg = l >> 4;

  const f32x4 zero = {0.f, 0.f, 0.f, 0.f};
  f32x4 accg[4][2], accu[4][2];
#pragma unroll
  for (int i = 0; i < 4; ++i)
#pragma unroll
    for (int j = 0; j < 2; ++j) { accg[i][j] = zero; accu[i][j] = zero; }

  for (int kt = 0; kt < H_DIM / 64; ++kt) {
    const int k0 = kt * 64;
#pragma unroll
    for (int j = 0; j < 4; ++j)
      gload16(A + arow[j] + k0, S + (w * 4 + j) * 512);
#pragma unroll
    for (int j = 0; j < 2; ++j) {
      const size_t br = (size_t)(w * 16 + j * 8 + r8) * H_DIM + sk + k0;
      gload16(Bgp + br, S + 8192 + (w * 2 + j) * 512);
      gload16(Bup + br, S + 12288 + (w * 2 + j) * 512);
    }
    __syncthreads();
    const u16* AsC = S;
    const u16* BgC = S + 8192;
    const u16* BuC = S + 12288;
#pragma unroll
    for (int kk = 0; kk < 2; ++kk) {
      const int kb = kk * 64 + fg * 16;
      bf16x8 af[4], bg[2], bu[2];
#pragma unroll
      for (int mi = 0; mi < 4; ++mi)
        af[mi] = *(const bf16x8*)lds_sw(AsC, wr * 64 + mi * 16 + fr, kb);
#pragma unroll
      for (int ni = 0; ni < 2; ++ni) {
        bg[ni] = *(const bf16x8*)lds_sw(BgC, wc * 32 + ni * 16 + fr, kb);
        bu[ni] = *(const bf16x8*)lds_sw(BuC, wc * 32 + ni * 16 + fr, kb);
      }
#pragma unroll
      for (int mi = 0; mi < 4; ++mi)
#pragma unroll
        for (int ni = 0; ni < 2; ++ni) {
          accg[mi][ni] = MFMA(af[mi], bg[ni], accg[mi][ni]);
          accu[mi][ni] = MFMA(af[mi], bu[ni], accu[mi][ni]);
        }
    }
    __syncthreads();
  }

  const int colb = n0 + wc * 32;
#pragma unroll
  for (int mi = 0; mi < 4; ++mi) {
#pragma unroll
    for (int r = 0; r < 4; ++r) {
      const int ml = wr * 64 + mi * 16 + fg * 4 + r;
      if (m0 + ml >= M) continue;
      const int trow = tok ? tok[e * T_TOK + m0 + ml] : (m0 + ml);
      const float wgt = comb ? comb[trow * E_NUM + e] : 1.0f;
      const size_t rowoff = (size_t)e * out_e_stride + (size_t)(m0 + ml) * out_stride;
#pragma unroll
      for (int ni = 0; ni < 2; ++ni) {
        float g = accg[mi][ni][r];
        float u = accu[mi][ni][r];
        float sg = g / (1.f + __expf(-g));
        outp[rowoff + colb + ni * 16 + fr] = f2bf(sg * u * wgt);
      }
    }
  }
}

// ---------------- mega kernel: gu_routed + gu_shared + transp(wd) + transp(wsd) ----------------
// Sequential block order (GEMM ids first): GEMM blocks pack CUs densely at the
// start (cross-block wave overlap), transposes fill behind. Do NOT interleave.
#define MG_GUR_BLKS (11 * 8 * 16) /* 1408 */
#define MG_GUS_BLKS (22 * 8)      /* 176  */
#define MG_TWD_BLKS (16 * 11 * 16)/* 2816: wd 64x128 tiles */
#define MG_TWSD_BLKS (16 * 22)    /* 352:  wsd 64x128 tiles */
__global__ __launch_bounds__(256, 4) void mega_k(
    const u16* __restrict__ XB, const u16* __restrict__ WGUT,
    const u16* __restrict__ WSGUT, const float* __restrict__ comb,
    const int* __restrict__ cnt, const int* __restrict__ tok,
    u16* __restrict__ ACTC, u16* __restrict__ ACTS,
    const float* __restrict__ wd, const float* __restrict__ wsd,
    u16* __restrict__ WDT, u16* __restrict__ WSDT) {
  __shared__ __align__(16) char SM[32768];
  const int bid = blockIdx.x;
  if (bid < MG_GUR_BLKS) {
    gu_body(XB, WGUT, comb, cnt, tok, ACTC, I_DIM, (long long)(2 * I_DIM) * H_DIM,
            (long long)T_TOK * I_DIM, I_DIM, bid % 11, (bid / 11) % 8, bid / 88, SM);
  } else if (bid < MG_GUR_BLKS + MG_GUS_BLKS) {
    const int id = bid - MG_GUR_BLKS;
    gu_body(XB, WSGUT, nullptr, nullptr, nullptr, ACTS, IS_DIM, 0, 0, IS_DIM,
            id % 22, id / 22, 0, SM);
  } else if (bid < MG_GUR_BLKS + MG_GUS_BLKS + MG_TWD_BLKS) {
    const int id = bid - MG_GUR_BLKS - MG_GUS_BLKS;
    transp_g_body(wd, WDT, I_DIM, H_DIM, id % 16, (id / 16) % 11, id / 176, SM);
  } else {
    const int id = bid - MG_GUR_BLKS - MG_GUS_BLKS - MG_TWD_BLKS;
    transp_g_body(wsd, WSDT, IS_DIM, H_DIM, id % 16, id / 16, 0, SM);
  }
}

// ---------------- down GEMM core: BM=64, BN=128, single-buffer gload_lds, atomic ----------------
__device__ __forceinline__ void down_core_atomic(
    const u16* __restrict__ Ap, int astride,
    const u16* __restrict__ Bp, int bstride,
    int NT, int M, int m0, int n0, const int* tokS, float* __restrict__ outp) {
  __shared__ __align__(16) u16 S[12288]; // As 4096, Bs 8192
  const int tid = threadIdx.x;
  const int w = tid >> 6, l = tid & 63;
  const int r8 = l >> 3;
  const int sk = ((l & 7) ^ r8) * 8;

  size_t arow[2];
#pragma unroll
  for (int j = 0; j < 2; ++j) {
    const int m = w * 16 + j * 8 + r8;
    arow[j] = (size_t)(m0 + m < M ? m : (M - 1 - m0 > 0 ? M - 1 - m0 : 0)) * astride + sk;
  }
  size_t brow[4];
#pragma unroll
  for (int j = 0; j < 4; ++j)
    brow[j] = (size_t)(w * 32 + j * 8 + r8) * bstride + sk;

  const int fr = l & 15, fg = l >> 4;
  const f32x4 zero = {0.f, 0.f, 0.f, 0.f};
  f32x4 acc[4][2];
#pragma unroll
  for (int i = 0; i < 4; ++i)
#pragma unroll
    for (int j = 0; j < 2; ++j) acc[i][j] = zero;

  for (int kt = 0; kt < NT; ++kt) {
    const int k0 = kt * 64;
#pragma unroll
    for (int j = 0; j < 2; ++j)
      gload16(Ap + arow[j] + k0, S + (w * 2 + j) * 512);
#pragma unroll
    for (int j = 0; j < 4; ++j)
      gload16(Bp + brow[j] + k0, S + 4096 + (w * 4 + j) * 512);
    __syncthreads();
    const u16* AsC = S;
    const u16* BsC = S + 4096;
#pragma unroll
    for (int kk = 0; kk < 2; ++kk) {
      const int kb = kk * 64 + fg * 16;
      bf16x8 af[4], bfr[2];
#pragma unroll
      for (int mi = 0; mi < 4; ++mi)
        af[mi] = *(const bf16x8*)lds_sw(AsC, mi * 16 + fr, kb);
#pragma unroll
      for (int ni = 0; ni < 2; ++ni)
        bfr[ni] = *(const bf16x8*)lds_sw(BsC, w * 32 + ni * 16 + fr, kb);
#pragma unroll
      for (int mi = 0; mi < 4; ++mi)
#pragma unroll
        for (int ni = 0; ni < 2; ++ni) acc[mi][ni] = MFMA(af[mi], bfr[ni], acc[mi][ni]);
    }
    __syncthreads();
  }

#pragma unroll
  for (int mi = 0; mi < 4; ++mi) {
#pragma unroll
    for (int r = 0; r < 4; ++r) {
      const int ml = mi * 16 + fg * 4 + r;
      if (m0 + ml >= M) continue;
      float* op = outp + (size_t)tokS[ml] * H_DIM + n0 + w * 32;
#pragma unroll
      for (int ni = 0; ni < 2; ++ni)
        atomicAdd(op + ni * 16 + fr, acc[mi][ni][r]);
    }
  }
}

// single down launch: z=0..15 routed experts, z=16 shared; all atomic into
// the pre-zeroed output (zeroed by fused_pre_k; same-stream ordering).
__global__ __launch_bounds__(256, 4) void down_all_k(
    const u16* __restrict__ ACTC, const u16* __restrict__ WDT,
    const u16* __restrict__ ACTS, const u16* __restrict__ WSDT,
    const int* __restrict__ cnt, const int* __restrict__ tok,
    float* __restrict__ outp) {
  const int e = blockIdx.z;
  const bool shared = (e == E_NUM);
  const int M = shared ? T_TOK : cnt[e];
  const int m0 = blockIdx.y * 64;
  if (m0 >= M) return;
  const int n0 = blockIdx.x * 128;
  __shared__ int tokS[64];
  const int tid = threadIdx.x;
  if (tid < 64) {
    const int m = m0 + tid;
    tokS[tid] = shared ? m : tok[e * T_TOK + (m < M ? m : M - 1)];
  }
  __syncthreads();
  if (shared)
    down_core_atomic(ACTS + (size_t)m0 * IS_DIM, IS_DIM,
                     WSDT + (size_t)n0 * IS_DIM, IS_DIM,
                     IS_DIM / 64, M, m0, n0, tokS, outp);
  else
    down_core_atomic(ACTC + ((size_t)e * T_TOK + m0) * I_DIM, I_DIM,
                     WDT + ((size_t)e * H_DIM + n0) * I_DIM, I_DIM,
                     I_DIM / 64, M, m0, n0, tokS, outp);
}

extern "C" void kernel_launch(void* const* d_in, const int* in_sizes, int n_in,
                              void* d_out, int out_size, void* d_ws, size_t ws_size,
                              hipStream_t stream) {
  const float* x    = (const float*)d_in[0];
  const float* wg   = (const float*)d_in[1];
  const float* wgu  = (const float*)d_in[2];
  const float* wd   = (const float*)d_in[3];
  const float* wsgu = (const float*)d_in[4];
  const float* wsd  = (const float*)d_in[5];
  float* out = (float*)d_out;

  char* ws = (char*)d_ws;
  size_t off = 0;
  auto alloc = [&](size_t b) { size_t r = off; off += (b + 255) & ~(size_t)255; return r; };
  u16*   XB    = (u16*)  (ws + alloc((size_t)T_TOK * H_DIM * 2));
  float* COMB  = (float*)(ws + alloc((size_t)T_TOK * E_NUM * 4));
  int*   CNT   = (int*)  (ws + alloc((size_t)E_NUM * 4));
  int*   TOK   = (int*)  (ws + alloc((size_t)E_NUM * T_TOK * 4));
  u16*   WGUT  = (u16*)  (ws + alloc((size_t)E_NUM * 2 * I_DIM * H_DIM * 2)); // [e][1408][2048]
  u16*   WDT   = (u16*)  (ws + alloc((size_t)E_NUM * H_DIM * I_DIM * 2));     // [e][2048][704]
  u16*   WSGUT = (u16*)  (ws + alloc((size_t)2 * IS_DIM * H_DIM * 2));        // [2816][2048]
  u16*   WSDT  = (u16*)  (ws + alloc((size_t)H_DIM * IS_DIM * 2));            // [2048][1408]
  u16*   ACTC  = (u16*)  (ws + alloc((size_t)E_NUM * T_TOK * I_DIM * 2));     // [e][1024][704]
  u16*   ACTS  = (u16*)  (ws + alloc((size_t)T_TOK * IS_DIM * 2));            // [1024][1408]
  if (ws_size < off) return;

  // fused pre-pass: router (+x->bf16) + out-zero + wgu/wsgu transposes
  fused_pre_k<<<FP_ROUTER + FP_ZERO + FP_WGU + FP_WSGU, 256, 0, stream>>>(
      x, wg, COMB, XB, wgu, wsgu, WGUT, WSGUT, out);
  dispatch_k<<<E_NUM, 256, 0, stream>>>(COMB, CNT, TOK);
  // mega: routed gu + shared gu GEMMs first, wd/wsd transposes fill behind
  mega_k<<<MG_GUR_BLKS + MG_GUS_BLKS + MG_TWD_BLKS + MG_TWSD_BLKS, 256, 0, stream>>>(
      XB, WGUT, WSGUT, COMB, CNT, TOK, ACTC, ACTS, wd, wsd, WDT, WSDT);
  // single all-atomic down pass (routed z=0..15, shared z=16) into zeroed out
  down_all_k<<<dim3(H_DIM / 128, T_TOK / 64, E_NUM + 1), 256, 0, stream>>>(
      ACTC, WDT, ACTS, WSDT, CNT, TOK, out);
}

// Round 18
// 247.003 us; speedup vs baseline: 1.0175x; 1.0092x over previous
//
#include <hip/hip_runtime.h>

typedef unsigned short u16;
typedef u16 u16x8 __attribute__((ext_vector_type(8)));
typedef __bf16 bf16x8 __attribute__((ext_vector_type(8)));
typedef float f32x4 __attribute__((ext_vector_type(4)));
typedef unsigned u32x2 __attribute__((ext_vector_type(2)));

#define T_TOK 1024
#define H_DIM 2048
#define E_NUM 16
#define I_DIM 704
#define IS_DIM 1408

#define MFMA(a, b, c) __builtin_amdgcn_mfma_f32_16x16x32_bf16(a, b, c, 0, 0, 0)

__device__ __forceinline__ u16 f2bf(float f) {
  union { float f; unsigned u; } v; v.f = f;
  unsigned r = v.u + 0x7fffu + ((v.u >> 16) & 1u);
  return (u16)(r >> 16);
}

// async global->LDS 16B per lane; dest wave-uniform base + lane*16
__device__ __forceinline__ void gload16(const void* g, void* l) {
  __builtin_amdgcn_global_load_lds(
      (const __attribute__((address_space(1))) unsigned int*)g,
      (__attribute__((address_space(3))) unsigned int*)l, 16, 0, 0);
}

// Swizzled LDS read address within 128-byte rows: XOR bits[6:4] with (row&7).
__device__ __forceinline__ const char* lds_sw(const u16* base, int row, int kByte) {
  return (const char*)base + row * 128 + (kByte ^ ((row & 7) << 4));
}

// ---------------- transpose+convert to TILE-BLOCKED layout ----------------
// Input [Rk][Cn] f32 (k-major weights). Block = 64 k-rows x 128 n-cols ->
// TWO output tiles [64n][64k] bf16 (8KB each), written as dense sequential
// streams (512B per wave-instr). Tile (nt,kt) lives at (nt*NTK+kt)*4096 elems.
// Staging via fire-and-forget gload_lds, chunk-XOR swizzled source (r17).
__device__ __forceinline__ void transp_tile_body(const float* __restrict__ in_e,
                                                 u16* __restrict__ out_e, int Cn,
                                                 int NTK, int cx, int ry, char* SM) {
  const int c0 = cx * 128, r0 = ry * 64;
  const int tid = threadIdx.x;
  const int w = tid >> 6;
#pragma unroll
  for (int j = 0; j < 8; ++j) {
    const int d = j * 256 + tid;          // 16B-chunk index, linear LDS order
    const int row = d >> 5, cp = d & 31;  // 32 chunks per 512B k-row
    const int c = cp ^ (row & 31);        // inverse-swizzled source chunk
    gload16(in_e + (size_t)(r0 + row) * Cn + c0 + c * 4,
            SM + (size_t)(j * 256 + w * 64) * 16);
  }
  __syncthreads();
#pragma unroll
  for (int i = 0; i < 8; ++i) {
    const int idx = i * 256 + tid;
    const int oc = idx >> 4, pp = idx & 15; // n-col (0..127), k row-quad
    float f[4];
#pragma unroll
    for (int k = 0; k < 4; ++k) {
      const int r = 4 * pp + k;
      f[k] = *(const float*)(SM + r * 512 + ((((oc >> 2) ^ (r & 31)) << 4)) +
                             (oc & 3) * 4);
    }
    u32x2 wv;
    wv[0] = (unsigned)f2bf(f[0]) | ((unsigned)f2bf(f[1]) << 16);
    wv[1] = (unsigned)f2bf(f[2]) | ((unsigned)f2bf(f[3]) << 16);
    const size_t tbase = (size_t)(((c0 >> 6) + (oc >> 6)) * NTK + ry) * 4096;
    *(u32x2*)&out_e[tbase + (oc & 63) * 64 + 4 * pp] = wv;
  }
}

// ---------------- router body (one block per token) + x->bf16 convert ----------------
__device__ __forceinline__ void router_body(const float* __restrict__ x,
                                            const float* __restrict__ wg,
                                            float* __restrict__ comb,
                                            u16* __restrict__ XB, int t, char* SM) {
  const int tid = threadIdx.x;
  const float* xr = x + (size_t)t * H_DIM;
  const int h0 = tid * 8;
  f32x4 a = *(const f32x4*)(xr + h0);
  f32x4 b = *(const f32x4*)(xr + h0 + 4);
  u16x8 o;
  o[0] = f2bf(a[0]); o[1] = f2bf(a[1]); o[2] = f2bf(a[2]); o[3] = f2bf(a[3]);
  o[4] = f2bf(b[0]); o[5] = f2bf(b[1]); o[6] = f2bf(b[2]); o[7] = f2bf(b[3]);
  *(u16x8*)(XB + (size_t)t * H_DIM + h0) = o;

  float acc[E_NUM];
#pragma unroll
  for (int e = 0; e < E_NUM; ++e) acc[e] = 0.f;
#pragma unroll
  for (int j = 0; j < 8; ++j) {
    const float xv = j < 4 ? a[j] : b[j - 4];
    const f32x4* wr = (const f32x4*)(wg + (size_t)(h0 + j) * E_NUM);
#pragma unroll
    for (int q = 0; q < 4; ++q) {
      f32x4 w4 = wr[q];
      acc[q * 4 + 0] += xv * w4[0];
      acc[q * 4 + 1] += xv * w4[1];
      acc[q * 4 + 2] += xv * w4[2];
      acc[q * 4 + 3] += xv * w4[3];
    }
  }
#pragma unroll
  for (int e = 0; e < E_NUM; ++e)
    for (int off = 32; off > 0; off >>= 1) acc[e] += __shfl_down(acc[e], off);
  float (*part)[E_NUM] = (float(*)[E_NUM])SM;
  if ((tid & 63) == 0) {
#pragma unroll
    for (int e = 0; e < E_NUM; ++e) part[tid >> 6][e] = acc[e];
  }
  __syncthreads();
  if (tid == 0) {
    float p[E_NUM];
    float mx = -1e30f;
    for (int e = 0; e < E_NUM; ++e) {
      p[e] = part[0][e] + part[1][e] + part[2][e] + part[3][e];
      mx = fmaxf(mx, p[e]);
    }
    float s = 0.f;
    for (int e = 0; e < E_NUM; ++e) { p[e] = __expf(p[e] - mx); s += p[e]; }
    const float invs = 1.f / s;
    for (int e = 0; e < E_NUM; ++e) p[e] *= invs;
    float gs[4];
    for (int g = 0; g < 4; ++g)
      gs[g] = fmaxf(fmaxf(p[4 * g], p[4 * g + 1]), fmaxf(p[4 * g + 2], p[4 * g + 3]));
    int g1 = 0;
    for (int g = 1; g < 4; ++g) if (gs[g] > gs[g1]) g1 = g;
    int g2 = -1;
    for (int g = 0; g < 4; ++g) {
      if (g == g1) continue;
      if (g2 < 0 || gs[g] > gs[g2]) g2 = g;
    }
    float m2[E_NUM], cw[E_NUM];
    for (int e = 0; e < E_NUM; ++e) {
      int g = e >> 2;
      m2[e] = (g == g1 || g == g2) ? p[e] : 0.f;
      cw[e] = 0.f;
    }
    float sum6 = 0.f;
    for (int k = 0; k < 6; ++k) {
      int bi = 0; float bv = -1.f;
      for (int e = 0; e < E_NUM; ++e)
        if (m2[e] > bv) { bv = m2[e]; bi = e; }
      cw[bi] = bv; sum6 += bv; m2[bi] = -2.f;
    }
    const float scale = 2.5f / sum6;
    for (int e = 0; e < E_NUM; ++e) comb[t * E_NUM + e] = cw[e] * scale;
  }
}

// ---------------- fused pre-pass: router + out-zero + wgu/wsgu transposes ----------------
#define FP_ROUTER T_TOK                 /* 1024 */
#define FP_ZERO 512                     /* 8.4MB out zero */
#define FP_WGU (11 * 32 * 16)           /* 5632: wgu 64k x 128n tiles */
#define FP_WSGU (22 * 32)               /* 704:  wsgu */
__global__ __launch_bounds__(256) void fused_pre_k(
    const float* __restrict__ x, const float* __restrict__ wg,
    float* __restrict__ comb, u16* __restrict__ XB,
    const float* __restrict__ wgu, const float* __restrict__ wsgu,
    u16* __restrict__ WGUT, u16* __restrict__ WSGUT, float* __restrict__ outz) {
  __shared__ __align__(16) char SM[32768];
  const int bid = blockIdx.x;
  if (bid < FP_ROUTER) {
    router_body(x, wg, comb, XB, bid, SM);
  } else if (bid < FP_ROUTER + FP_ZERO) {
    const int i = ((bid - FP_ROUTER) * 256 + threadIdx.x) * 16;
    const f32x4 z = {0.f, 0.f, 0.f, 0.f};
#pragma unroll
    for (int j = 0; j < 4; ++j) *(f32x4*)(outz + i + j * 4) = z;
  } else if (bid < FP_ROUTER + FP_ZERO + FP_WGU) {
    const int id = bid - FP_ROUTER - FP_ZERO;
    const int e = id / 352;
    transp_tile_body(wgu + (size_t)e * H_DIM * 2 * I_DIM,
                     WGUT + (size_t)e * 2 * I_DIM * H_DIM, 2 * I_DIM, 32,
                     id % 11, (id / 11) % 32, SM);
  } else {
    const int id = bid - FP_ROUTER - FP_ZERO - FP_WGU;
    transp_tile_body(wsgu, WSGUT, 2 * IS_DIM, 32, id % 22, id / 22, SM);
  }
}

// ---------------- dispatch: per-expert ordered token lists (no atomics) ----------------
__global__ __launch_bounds__(256) void dispatch_k(const float* __restrict__ comb,
                                                  int* __restrict__ cnt,
                                                  int* __restrict__ tok) {
  const int e = blockIdx.x;
  const int tid = threadIdx.x;
  const int lane = tid & 63, wid = tid >> 6;
  __shared__ int wtot[4];
  int running = 0;
  for (int chunk = 0; chunk < T_TOK / 256; ++chunk) {
    const int t = chunk * 256 + tid;
    const bool sel = comb[t * E_NUM + e] > 0.f;
    unsigned long long mask = __ballot(sel);
    const int pre = __popcll(mask & ((1ull << lane) - 1ull));
    if (lane == 0) wtot[wid] = __popcll(mask);
    __syncthreads();
    int wbase = running;
    for (int w = 0; w < wid; ++w) wbase += wtot[w];
    if (sel) tok[e * T_TOK + wbase + pre] = t;
    running += wtot[0] + wtot[1] + wtot[2] + wtot[3];
    __syncthreads();
  }
  if (tid == 0) cnt[e] = running;
}

// ---------------- fused gate/up GEMM body (m97; B in tile-blocked layout) ----------------
// B tile (nt,kt) at Bte[(nt*32 + kt)*4096]; staging source = tile + row*64 + sk
// (sequential 8KB tile reads, kt-ascending = contiguous 128KB stream).
__device__ __forceinline__ void gu_body(
    const u16* __restrict__ A, const u16* __restrict__ Bt,
    const float* __restrict__ comb, const int* __restrict__ cnt,
    const int* __restrict__ tok, u16* __restrict__ outp,
    int gu_off_t, long long bt_e_stride, long long out_e_stride, int out_stride,
    int bx, int by, int e, char* SM) {
  const int M = cnt ? cnt[e] : T_TOK;
  const int m0 = by * 128;
  if (m0 >= M) return;
  u16* S = (u16*)SM; // As 8192, Bg 4096, Bu 4096 (u16 counts) = 32768 B

  const int n0 = bx * 64;
  const u16* Bte = Bt + (size_t)e * bt_e_stride;
  const u16* Bgp = Bte + (size_t)((n0 >> 6) * 32) * 4096;
  const u16* Bup = Bte + (size_t)((gu_off_t + (n0 >> 6)) * 32) * 4096;
  const int tid = threadIdx.x;
  const int w = tid >> 6, l = tid & 63;
  const int r8 = l >> 3;
  const int sk = ((l & 7) ^ r8) * 8; // inverse-swizzled source k offset (elems)

  size_t arow[4];
#pragma unroll
  for (int j = 0; j < 4; ++j) {
    const int m = m0 + w * 32 + j * 8 + r8;
    const int mc = m < M ? m : M - 1;
    const int t = tok ? tok[e * T_TOK + mc] : mc;
    arow[j] = (size_t)t * H_DIM + sk;
  }
  const int browoff[2] = {(w * 16 + 0 + r8) * 64 + sk, (w * 16 + 8 + r8) * 64 + sk};

  const int wr = tid >> 7;
  const int wc = (tid >> 6) & 1;
  const int fr = l & 15;
  const int fg = l >> 4;

  const f32x4 zero = {0.f, 0.f, 0.f, 0.f};
  f32x4 accg[4][2], accu[4][2];
#pragma unroll
  for (int i = 0; i < 4; ++i)
#pragma unroll
    for (int j = 0; j < 2; ++j) { accg[i][j] = zero; accu[i][j] = zero; }

  for (int kt = 0; kt < H_DIM / 64; ++kt) {
    const int k0 = kt * 64;
    const int tb = kt * 4096;
#pragma unroll
    for (int j = 0; j < 4; ++j)
      gload16(A + arow[j] + k0, S + (w * 4 + j) * 512);
#pragma unroll
    for (int j = 0; j < 2; ++j) {
      gload16(Bgp + tb + browoff[j], S + 8192 + (w * 2 + j) * 512);
      gload16(Bup + tb + browoff[j], S + 12288 + (w * 2 + j) * 512);
    }
    __syncthreads();
    const u16* AsC = S;
    const u16* BgC = S + 8192;
    const u16* BuC = S + 12288;
#pragma unroll
    for (int kk = 0; kk < 2; ++kk) {
      const int kb = kk * 64 + fg * 16;
      bf16x8 af[4], bg[2], bu[2];
#pragma unroll
      for (int mi = 0; mi < 4; ++mi)
        af[mi] = *(const bf16x8*)lds_sw(AsC, wr * 64 + mi * 16 + fr, kb);
#pragma unroll
      for (int ni = 0; ni < 2; ++ni) {
        bg[ni] = *(const bf16x8*)lds_sw(BgC, wc * 32 + ni * 16 + fr, kb);
        bu[ni] = *(const bf16x8*)lds_sw(BuC, wc * 32 + ni * 16 + fr, kb);
      }
#pragma unroll
      for (int mi = 0; mi < 4; ++mi)
#pragma unroll
        for (int ni = 0; ni < 2; ++ni) {
          accg[mi][ni] = MFMA(af[mi], bg[ni], accg[mi][ni]);
          accu[mi][ni] = MFMA(af[mi], bu[ni], accu[mi][ni]);
        }
    }
    __syncthreads();
  }

  const int colb = n0 + wc * 32;
#pragma unroll
  for (int mi = 0; mi < 4; ++mi) {
#pragma unroll
    for (int r = 0; r < 4; ++r) {
      const int ml = wr * 64 + mi * 16 + fg * 4 + r;
      if (m0 + ml >= M) continue;
      const int trow = tok ? tok[e * T_TOK + m0 + ml] : (m0 + ml);
      const float wgt = comb ? comb[trow * E_NUM + e] : 1.0f;
      const size_t rowoff = (size_t)e * out_e_stride + (size_t)(m0 + ml) * out_stride;
#pragma unroll
      for (int ni = 0; ni < 2; ++ni) {
        float g = accg[mi][ni][r];
        float u = accu[mi][ni][r];
        float sg = g / (1.f + __expf(-g));
        outp[rowoff + colb + ni * 16 + fr] = f2bf(sg * u * wgt);
      }
    }
  }
}

// ---------------- mega kernel: gu_routed + gu_shared + transp(wd) + transp(wsd) ----------------
#define MG_GUR_BLKS (11 * 8 * 16) /* 1408 */
#define MG_GUS_BLKS (22 * 8)      /* 176  */
#define MG_TWD_BLKS (16 * 11 * 16)/* 2816: wd 64k x 128n tiles */
#define MG_TWSD_BLKS (16 * 22)    /* 352:  wsd */
__global__ __launch_bounds__(256, 4) void mega_k(
    const u16* __restrict__ XB, const u16* __restrict__ WGUT,
    const u16* __restrict__ WSGUT, const float* __restrict__ comb,
    const int* __restrict__ cnt, const int* __restrict__ tok,
    u16* __restrict__ ACTC, u16* __restrict__ ACTS,
    const float* __restrict__ wd, const float* __restrict__ wsd,
    u16* __restrict__ WDT, u16* __restrict__ WSDT) {
  __shared__ __align__(16) char SM[32768];
  const int bid = blockIdx.x;
  if (bid < MG_GUR_BLKS) {
    gu_body(XB, WGUT, comb, cnt, tok, ACTC, I_DIM / 64,
            (long long)(2 * I_DIM) * H_DIM, (long long)T_TOK * I_DIM, I_DIM,
            bid % 11, (bid / 11) % 8, bid / 88, SM);
  } else if (bid < MG_GUR_BLKS + MG_GUS_BLKS) {
    const int id = bid - MG_GUR_BLKS;
    gu_body(XB, WSGUT, nullptr, nullptr, nullptr, ACTS, IS_DIM / 64, 0, 0, IS_DIM,
            id % 22, id / 22, 0, SM);
  } else if (bid < MG_GUR_BLKS + MG_GUS_BLKS + MG_TWD_BLKS) {
    const int id = bid - MG_GUR_BLKS - MG_GUS_BLKS;
    const int e = id / 176;
    transp_tile_body(wd + (size_t)e * I_DIM * H_DIM,
                     WDT + (size_t)e * H_DIM * I_DIM, H_DIM, 11,
                     id % 16, (id / 16) % 11, SM);
  } else {
    const int id = bid - MG_GUR_BLKS - MG_GUS_BLKS - MG_TWD_BLKS;
    transp_tile_body(wsd, WSDT, H_DIM, 22, id % 16, id / 16, SM);
  }
}

// ---------------- down GEMM core: BM=64, BN=128, tile-blocked B, atomic ----------------
__device__ __forceinline__ void down_core_atomic(
    const u16* __restrict__ Ap, int astride, const u16* __restrict__ Bp, int NTK,
    int NT, int M, int m0, int n0, const int* tokS, float* __restrict__ outp) {
  __shared__ __align__(16) u16 S[12288]; // As 4096, Bs 8192
  const int tid = threadIdx.x;
  const int w = tid >> 6, l = tid & 63;
  const int r8 = l >> 3;
  const int sk = ((l & 7) ^ r8) * 8;

  size_t arow[2];
#pragma unroll
  for (int j = 0; j < 2; ++j) {
    const int m = w * 16 + j * 8 + r8;
    arow[j] = (size_t)(m0 + m < M ? m : (M - 1 - m0 > 0 ? M - 1 - m0 : 0)) * astride + sk;
  }
  size_t brow[4];
#pragma unroll
  for (int j = 0; j < 4; ++j) {
    const int row = w * 32 + j * 8 + r8; // 0..127 across BN=128 (2 n-tiles)
    brow[j] = (size_t)((row >> 6) * NTK) * 4096 + (row & 63) * 64 + sk;
  }

  const int fr = l & 15, fg = l >> 4;
  const f32x4 zero = {0.f, 0.f, 0.f, 0.f};
  f32x4 acc[4][2];
#pragma unroll
  for (int i = 0; i < 4; ++i)
#pragma unroll
    for (int j = 0; j < 2; ++j) acc[i][j] = zero;

  for (int kt = 0; kt < NT; ++kt) {
    const int k0 = kt * 64;
    const int tb = kt * 4096;
#pragma unroll
    for (int j = 0; j < 2; ++j)
      gload16(Ap + arow[j] + k0, S + (w * 2 + j) * 512);
#pragma unroll
    for (int j = 0; j < 4; ++j)
      gload16(Bp + brow[j] + tb, S + 4096 + (w * 4 + j) * 512);
    __syncthreads();
    const u16* AsC = S;
    const u16* BsC = S + 4096;
#pragma unroll
    for (int kk = 0; kk < 2; ++kk) {
      const int kb = kk * 64 + fg * 16;
      bf16x8 af[4], bfr[2];
#pragma unroll
      for (int mi = 0; mi < 4; ++mi)
        af[mi] = *(const bf16x8*)lds_sw(AsC, mi * 16 + fr, kb);
#pragma unroll
      for (int ni = 0; ni < 2; ++ni)
        bfr[ni] = *(const bf16x8*)lds_sw(BsC, w * 32 + ni * 16 + fr, kb);
#pragma unroll
      for (int mi = 0; mi < 4; ++mi)
#pragma unroll
        for (int ni = 0; ni < 2; ++ni) acc[mi][ni] = MFMA(af[mi], bfr[ni], acc[mi][ni]);
    }
    __syncthreads();
  }

#pragma unroll
  for (int mi = 0; mi < 4; ++mi) {
#pragma unroll
    for (int r = 0; r < 4; ++r) {
      const int ml = mi * 16 + fg * 4 + r;
      if (m0 + ml >= M) continue;
      float* op = outp + (size_t)tokS[ml] * H_DIM + n0 + w * 32;
#pragma unroll
      for (int ni = 0; ni < 2; ++ni)
        atomicAdd(op + ni * 16 + fr, acc[mi][ni][r]);
    }
  }
}

// single down launch: z=0..15 routed experts, z=16 shared; all atomic into
// the pre-zeroed output (zeroed by fused_pre_k; same-stream ordering).
__global__ __launch_bounds__(256, 4) void down_all_k(
    const u16* __restrict__ ACTC, const u16* __restrict__ WDT,
    const u16* __restrict__ ACTS, const u16* __restrict__ WSDT,
    const int* __restrict__ cnt, const int* __restrict__ tok,
    float* __restrict__ outp) {
  const int e = blockIdx.z;
  const bool shared = (e == E_NUM);
  const int M = shared ? T_TOK : cnt[e];
  const int m0 = blockIdx.y * 64;
  if (m0 >= M) return;
  const int n0 = blockIdx.x * 128;
  __shared__ int tokS[64];
  const int tid = threadIdx.x;
  if (tid < 64) {
    const int m = m0 + tid;
    tokS[tid] = shared ? m : tok[e * T_TOK + (m < M ? m : M - 1)];
  }
  __syncthreads();
  if (shared)
    down_core_atomic(ACTS + (size_t)m0 * IS_DIM, IS_DIM,
                     WSDT + (size_t)((n0 >> 6) * 22) * 4096, 22,
                     IS_DIM / 64, M, m0, n0, tokS, outp);
  else
    down_core_atomic(ACTC + ((size_t)e * T_TOK + m0) * I_DIM, I_DIM,
                     WDT + (size_t)e * H_DIM * I_DIM +
                         (size_t)((n0 >> 6) * 11) * 4096, 11,
                     I_DIM / 64, M, m0, n0, tokS, outp);
}

extern "C" void kernel_launch(void* const* d_in, const int* in_sizes, int n_in,
                              void* d_out, int out_size, void* d_ws, size_t ws_size,
                              hipStream_t stream) {
  const float* x    = (const float*)d_in[0];
  const float* wg   = (const float*)d_in[1];
  const float* wgu  = (const float*)d_in[2];
  const float* wd   = (const float*)d_in[3];
  const float* wsgu = (const float*)d_in[4];
  const float* wsd  = (const float*)d_in[5];
  float* out = (float*)d_out;

  char* ws = (char*)d_ws;
  size_t off = 0;
  auto alloc = [&](size_t b) { size_t r = off; off += (b + 255) & ~(size_t)255; return r; };
  u16*   XB    = (u16*)  (ws + alloc((size_t)T_TOK * H_DIM * 2));
  float* COMB  = (float*)(ws + alloc((size_t)T_TOK * E_NUM * 4));
  int*   CNT   = (int*)  (ws + alloc((size_t)E_NUM * 4));
  int*   TOK   = (int*)  (ws + alloc((size_t)E_NUM * T_TOK * 4));
  u16*   WGUT  = (u16*)  (ws + alloc((size_t)E_NUM * 2 * I_DIM * H_DIM * 2)); // tiled [e][22nt][32kt][4096]
  u16*   WDT   = (u16*)  (ws + alloc((size_t)E_NUM * H_DIM * I_DIM * 2));     // tiled [e][32nt][11kt][4096]
  u16*   WSGUT = (u16*)  (ws + alloc((size_t)2 * IS_DIM * H_DIM * 2));        // tiled [44nt][32kt][4096]
  u16*   WSDT  = (u16*)  (ws + alloc((size_t)H_DIM * IS_DIM * 2));            // tiled [32nt][22kt][4096]
  u16*   ACTC  = (u16*)  (ws + alloc((size_t)E_NUM * T_TOK * I_DIM * 2));     // [e][1024][704]
  u16*   ACTS  = (u16*)  (ws + alloc((size_t)T_TOK * IS_DIM * 2));            // [1024][1408]
  if (ws_size < off) return;

  // fused pre-pass: router (+x->bf16) + out-zero + wgu/wsgu tile-transposes
  fused_pre_k<<<FP_ROUTER + FP_ZERO + FP_WGU + FP_WSGU, 256, 0, stream>>>(
      x, wg, COMB, XB, wgu, wsgu, WGUT, WSGUT, out);
  dispatch_k<<<E_NUM, 256, 0, stream>>>(COMB, CNT, TOK);
  // mega: routed gu + shared gu GEMMs first, wd/wsd tile-transposes fill behind
  mega_k<<<MG_GUR_BLKS + MG_GUS_BLKS + MG_TWD_BLKS + MG_TWSD_BLKS, 256, 0, stream>>>(
      XB, WGUT, WSGUT, COMB, CNT, TOK, ACTC, ACTS, wd, wsd, WDT, WSDT);
  // single all-atomic down pass (routed z=0..15, shared z=16) into zeroed out
  down_all_k<<<dim3(H_DIM / 128, T_TOK / 64, E_NUM + 1), 256, 0, stream>>>(
      ACTC, WDT, ACTS, WSDT, CNT, TOK, out);
}

// Round 19
// 225.997 us; speedup vs baseline: 1.1120x; 1.0929x over previous
//
#include <hip/hip_runtime.h>

typedef unsigned short u16;
typedef u16 u16x8 __attribute__((ext_vector_type(8)));
typedef __bf16 bf16x8 __attribute__((ext_vector_type(8)));
typedef float f32x4 __attribute__((ext_vector_type(4)));
typedef unsigned u32x2 __attribute__((ext_vector_type(2)));

#define T_TOK 1024
#define H_DIM 2048
#define E_NUM 16
#define I_DIM 704
#define IS_DIM 1408

#define MFMA(a, b, c) __builtin_amdgcn_mfma_f32_16x16x32_bf16(a, b, c, 0, 0, 0)

__device__ __forceinline__ u16 f2bf(float f) {
  union { float f; unsigned u; } v; v.f = f;
  unsigned r = v.u + 0x7fffu + ((v.u >> 16) & 1u);
  return (u16)(r >> 16);
}

// async global->LDS 16B per lane; dest wave-uniform base + lane*16
__device__ __forceinline__ void gload16(const void* g, void* l) {
  __builtin_amdgcn_global_load_lds(
      (const __attribute__((address_space(1))) unsigned int*)g,
      (__attribute__((address_space(3))) unsigned int*)l, 16, 0, 0);
}

// Swizzled LDS read address within 128-byte rows: XOR bits[6:4] with (row&7).
__device__ __forceinline__ const char* lds_sw(const u16* base, int row, int kByte) {
  return (const char*)base + row * 128 + (kByte ^ ((row & 7) << 4));
}

// ---------------- transpose+convert to TILE-BLOCKED layout ----------------
// Input [Rk][Cn] f32 (k-major weights). Block = 64 k-rows x 128 n-cols ->
// TWO output tiles [64n][64k] bf16 (8KB each), written as dense sequential
// streams. Staging via fire-and-forget gload_lds, chunk-XOR swizzled source.
__device__ __forceinline__ void transp_tile_body(const float* __restrict__ in_e,
                                                 u16* __restrict__ out_e, int Cn,
                                                 int NTK, int cx, int ry, char* SM) {
  const int c0 = cx * 128, r0 = ry * 64;
  const int tid = threadIdx.x;
  const int w = tid >> 6;
#pragma unroll
  for (int j = 0; j < 8; ++j) {
    const int d = j * 256 + tid;          // 16B-chunk index, linear LDS order
    const int row = d >> 5, cp = d & 31;  // 32 chunks per 512B k-row
    const int c = cp ^ (row & 31);        // inverse-swizzled source chunk
    gload16(in_e + (size_t)(r0 + row) * Cn + c0 + c * 4,
            SM + (size_t)(j * 256 + w * 64) * 16);
  }
  __syncthreads();
#pragma unroll
  for (int i = 0; i < 8; ++i) {
    const int idx = i * 256 + tid;
    const int oc = idx >> 4, pp = idx & 15; // n-col (0..127), k row-quad
    float f[4];
#pragma unroll
    for (int k = 0; k < 4; ++k) {
      const int r = 4 * pp + k;
      f[k] = *(const float*)(SM + r * 512 + ((((oc >> 2) ^ (r & 31)) << 4)) +
                             (oc & 3) * 4);
    }
    u32x2 wv;
    wv[0] = (unsigned)f2bf(f[0]) | ((unsigned)f2bf(f[1]) << 16);
    wv[1] = (unsigned)f2bf(f[2]) | ((unsigned)f2bf(f[3]) << 16);
    const size_t tbase = (size_t)(((c0 >> 6) + (oc >> 6)) * NTK + ry) * 4096;
    *(u32x2*)&out_e[tbase + (oc & 63) * 64 + 4 * pp] = wv;
  }
}

// ---------------- router body (one block per token) + x->bf16 convert ----------------
__device__ __forceinline__ void router_body(const float* __restrict__ x,
                                            const float* __restrict__ wg,
                                            float* __restrict__ comb,
                                            u16* __restrict__ XB, int t, char* SM) {
  const int tid = threadIdx.x;
  const float* xr = x + (size_t)t * H_DIM;
  const int h0 = tid * 8;
  f32x4 a = *(const f32x4*)(xr + h0);
  f32x4 b = *(const f32x4*)(xr + h0 + 4);
  u16x8 o;
  o[0] = f2bf(a[0]); o[1] = f2bf(a[1]); o[2] = f2bf(a[2]); o[3] = f2bf(a[3]);
  o[4] = f2bf(b[0]); o[5] = f2bf(b[1]); o[6] = f2bf(b[2]); o[7] = f2bf(b[3]);
  *(u16x8*)(XB + (size_t)t * H_DIM + h0) = o;

  float acc[E_NUM];
#pragma unroll
  for (int e = 0; e < E_NUM; ++e) acc[e] = 0.f;
#pragma unroll
  for (int j = 0; j < 8; ++j) {
    const float xv = j < 4 ? a[j] : b[j - 4];
    const f32x4* wr = (const f32x4*)(wg + (size_t)(h0 + j) * E_NUM);
#pragma unroll
    for (int q = 0; q < 4; ++q) {
      f32x4 w4 = wr[q];
      acc[q * 4 + 0] += xv * w4[0];
      acc[q * 4 + 1] += xv * w4[1];
      acc[q * 4 + 2] += xv * w4[2];
      acc[q * 4 + 3] += xv * w4[3];
    }
  }
#pragma unroll
  for (int e = 0; e < E_NUM; ++e)
    for (int off = 32; off > 0; off >>= 1) acc[e] += __shfl_down(acc[e], off);
  float (*part)[E_NUM] = (float(*)[E_NUM])SM;
  if ((tid & 63) == 0) {
#pragma unroll
    for (int e = 0; e < E_NUM; ++e) part[tid >> 6][e] = acc[e];
  }
  __syncthreads();
  if (tid == 0) {
    float p[E_NUM];
    float mx = -1e30f;
    for (int e = 0; e < E_NUM; ++e) {
      p[e] = part[0][e] + part[1][e] + part[2][e] + part[3][e];
      mx = fmaxf(mx, p[e]);
    }
    float s = 0.f;
    for (int e = 0; e < E_NUM; ++e) { p[e] = __expf(p[e] - mx); s += p[e]; }
    const float invs = 1.f / s;
    for (int e = 0; e < E_NUM; ++e) p[e] *= invs;
    float gs[4];
    for (int g = 0; g < 4; ++g)
      gs[g] = fmaxf(fmaxf(p[4 * g], p[4 * g + 1]), fmaxf(p[4 * g + 2], p[4 * g + 3]));
    int g1 = 0;
    for (int g = 1; g < 4; ++g) if (gs[g] > gs[g1]) g1 = g;
    int g2 = -1;
    for (int g = 0; g < 4; ++g) {
      if (g == g1) continue;
      if (g2 < 0 || gs[g] > gs[g2]) g2 = g;
    }
    float m2[E_NUM], cw[E_NUM];
    for (int e = 0; e < E_NUM; ++e) {
      int g = e >> 2;
      m2[e] = (g == g1 || g == g2) ? p[e] : 0.f;
      cw[e] = 0.f;
    }
    float sum6 = 0.f;
    for (int k = 0; k < 6; ++k) {
      int bi = 0; float bv = -1.f;
      for (int e = 0; e < E_NUM; ++e)
        if (m2[e] > bv) { bv = m2[e]; bi = e; }
      cw[bi] = bv; sum6 += bv; m2[bi] = -2.f;
    }
    const float scale = 2.5f / sum6;
    for (int e = 0; e < E_NUM; ++e) comb[t * E_NUM + e] = cw[e] * scale;
  }
}

// ---------------- fused pre-pass: router + out-zero + wgu/wsgu transposes ----------------
#define FP_ROUTER T_TOK                 /* 1024 */
#define FP_ZERO 512                     /* 8.4MB out zero */
#define FP_WGU (11 * 32 * 16)           /* 5632: wgu 64k x 128n tiles */
#define FP_WSGU (22 * 32)               /* 704:  wsgu */
__global__ __launch_bounds__(256) void fused_pre_k(
    const float* __restrict__ x, const float* __restrict__ wg,
    float* __restrict__ comb, u16* __restrict__ XB,
    const float* __restrict__ wgu, const float* __restrict__ wsgu,
    u16* __restrict__ WGUT, u16* __restrict__ WSGUT, float* __restrict__ outz) {
  __shared__ __align__(16) char SM[32768];
  const int bid = blockIdx.x;
  if (bid < FP_ROUTER) {
    router_body(x, wg, comb, XB, bid, SM);
  } else if (bid < FP_ROUTER + FP_ZERO) {
    const int i = ((bid - FP_ROUTER) * 256 + threadIdx.x) * 16;
    const f32x4 z = {0.f, 0.f, 0.f, 0.f};
#pragma unroll
    for (int j = 0; j < 4; ++j) *(f32x4*)(outz + i + j * 4) = z;
  } else if (bid < FP_ROUTER + FP_ZERO + FP_WGU) {
    const int id = bid - FP_ROUTER - FP_ZERO;
    const int e = id / 352;
    transp_tile_body(wgu + (size_t)e * H_DIM * 2 * I_DIM,
                     WGUT + (size_t)e * 2 * I_DIM * H_DIM, 2 * I_DIM, 32,
                     id % 11, (id / 11) % 32, SM);
  } else {
    const int id = bid - FP_ROUTER - FP_ZERO - FP_WGU;
    transp_tile_body(wsgu, WSGUT, 2 * IS_DIM, 32, id % 22, id / 22, SM);
  }
}

// ---------------- dispatch: per-expert ordered token lists (no atomics) ----------------
__global__ __launch_bounds__(256) void dispatch_k(const float* __restrict__ comb,
                                                  int* __restrict__ cnt,
                                                  int* __restrict__ tok) {
  const int e = blockIdx.x;
  const int tid = threadIdx.x;
  const int lane = tid & 63, wid = tid >> 6;
  __shared__ int wtot[4];
  int running = 0;
  for (int chunk = 0; chunk < T_TOK / 256; ++chunk) {
    const int t = chunk * 256 + tid;
    const bool sel = comb[t * E_NUM + e] > 0.f;
    unsigned long long mask = __ballot(sel);
    const int pre = __popcll(mask & ((1ull << lane) - 1ull));
    if (lane == 0) wtot[wid] = __popcll(mask);
    __syncthreads();
    int wbase = running;
    for (int w = 0; w < wid; ++w) wbase += wtot[w];
    if (sel) tok[e * T_TOK + wbase + pre] = t;
    running += wtot[0] + wtot[1] + wtot[2] + wtot[3];
    __syncthreads();
  }
  if (tid == 0) cnt[e] = running;
}

// ---------------- fused gate/up GEMM body (m97; B in tile-blocked layout) ----------------
__device__ __forceinline__ void gu_body(
    const u16* __restrict__ A, const u16* __restrict__ Bt,
    const float* __restrict__ comb, const int* __restrict__ cnt,
    const int* __restrict__ tok, u16* __restrict__ outp,
    int gu_off_t, long long bt_e_stride, long long out_e_stride, int out_stride,
    int bx, int by, int e, char* SM) {
  const int M = cnt ? cnt[e] : T_TOK;
  const int m0 = by * 128;
  if (m0 >= M) return;
  u16* S = (u16*)SM; // As 8192, Bg 4096, Bu 4096 (u16 counts) = 32768 B

  const int n0 = bx * 64;
  const u16* Bte = Bt + (size_t)e * bt_e_stride;
  const u16* Bgp = Bte + (size_t)((n0 >> 6) * 32) * 4096;
  const u16* Bup = Bte + (size_t)((gu_off_t + (n0 >> 6)) * 32) * 4096;
  const int tid = threadIdx.x;
  const int w = tid >> 6, l = tid & 63;
  const int r8 = l >> 3;
  const int sk = ((l & 7) ^ r8) * 8; // inverse-swizzled source k offset (elems)

  size_t arow[4];
#pragma unroll
  for (int j = 0; j < 4; ++j) {
    const int m = m0 + w * 32 + j * 8 + r8;
    const int mc = m < M ? m : M - 1;
    const int t = tok ? tok[e * T_TOK + mc] : mc;
    arow[j] = (size_t)t * H_DIM + sk;
  }
  const int browoff[2] = {(w * 16 + 0 + r8) * 64 + sk, (w * 16 + 8 + r8) * 64 + sk};

  const int wr = tid >> 7;
  const int wc = (tid >> 6) & 1;
  const int fr = l & 15;
  const int fg = l >> 4;

  const f32x4 zero = {0.f, 0.f, 0.f, 0.f};
  f32x4 accg[4][2], accu[4][2];
#pragma unroll
  for (int i = 0; i < 4; ++i)
#pragma unroll
    for (int j = 0; j < 2; ++j) { accg[i][j] = zero; accu[i][j] = zero; }

  for (int kt = 0; kt < H_DIM / 64; ++kt) {
    const int k0 = kt * 64;
    const int tb = kt * 4096;
#pragma unroll
    for (int j = 0; j < 4; ++j)
      gload16(A + arow[j] + k0, S + (w * 4 + j) * 512);
#pragma unroll
    for (int j = 0; j < 2; ++j) {
      gload16(Bgp + tb + browoff[j], S + 8192 + (w * 2 + j) * 512);
      gload16(Bup + tb + browoff[j], S + 12288 + (w * 2 + j) * 512);
    }
    __syncthreads();
    const u16* AsC = S;
    const u16* BgC = S + 8192;
    const u16* BuC = S + 12288;
#pragma unroll
    for (int kk = 0; kk < 2; ++kk) {
      const int kb = kk * 64 + fg * 16;
      bf16x8 af[4], bg[2], bu[2];
#pragma unroll
      for (int mi = 0; mi < 4; ++mi)
        af[mi] = *(const bf16x8*)lds_sw(AsC, wr * 64 + mi * 16 + fr, kb);
#pragma unroll
      for (int ni = 0; ni < 2; ++ni) {
        bg[ni] = *(const bf16x8*)lds_sw(BgC, wc * 32 + ni * 16 + fr, kb);
        bu[ni] = *(const bf16x8*)lds_sw(BuC, wc * 32 + ni * 16 + fr, kb);
      }
#pragma unroll
      for (int mi = 0; mi < 4; ++mi)
#pragma unroll
        for (int ni = 0; ni < 2; ++ni) {
          accg[mi][ni] = MFMA(af[mi], bg[ni], accg[mi][ni]);
          accu[mi][ni] = MFMA(af[mi], bu[ni], accu[mi][ni]);
        }
    }
    __syncthreads();
  }

  const int colb = n0 + wc * 32;
#pragma unroll
  for (int mi = 0; mi < 4; ++mi) {
#pragma unroll
    for (int r = 0; r < 4; ++r) {
      const int ml = wr * 64 + mi * 16 + fg * 4 + r;
      if (m0 + ml >= M) continue;
      const int trow = tok ? tok[e * T_TOK + m0 + ml] : (m0 + ml);
      const float wgt = comb ? comb[trow * E_NUM + e] : 1.0f;
      const size_t rowoff = (size_t)e * out_e_stride + (size_t)(m0 + ml) * out_stride;
#pragma unroll
      for (int ni = 0; ni < 2; ++ni) {
        float g = accg[mi][ni][r];
        float u = accu[mi][ni][r];
        float sg = g / (1.f + __expf(-g));
        outp[rowoff + colb + ni * 16 + fr] = f2bf(sg * u * wgt);
      }
    }
  }
}

// ---------------- mega kernel: gu_routed + gu_shared + transp(wd) + transp(wsd) ----------------
// Routed-gu remap (T1): id = my*176 + (e*11+nx). my-stride 176 % 8 == 0, so
// the 8 m-tiles sharing an (e,nx) B-panel (512KB, L2-fit) land on the SAME XCD
// -> panel served from that XCD's L2 instead of L3 re-reads. (down_all already
// has this property: its same-panel blocks are stride-16 apart.)
#define MG_GUR_BLKS (11 * 8 * 16) /* 1408 = 176 panels x 8 m-tiles */
#define MG_GUS_BLKS (22 * 8)      /* 176  */
#define MG_TWD_BLKS (16 * 11 * 16)/* 2816: wd 64k x 128n tiles */
#define MG_TWSD_BLKS (16 * 22)    /* 352:  wsd */
__global__ __launch_bounds__(256, 4) void mega_k(
    const u16* __restrict__ XB, const u16* __restrict__ WGUT,
    const u16* __restrict__ WSGUT, const float* __restrict__ comb,
    const int* __restrict__ cnt, const int* __restrict__ tok,
    u16* __restrict__ ACTC, u16* __restrict__ ACTS,
    const float* __restrict__ wd, const float* __restrict__ wsd,
    u16* __restrict__ WDT, u16* __restrict__ WSDT) {
  __shared__ __align__(16) char SM[32768];
  const int bid = blockIdx.x;
  if (bid < MG_GUR_BLKS) {
    const int my = bid / 176, pe = bid % 176;
    const int e = pe / 11, nx = pe % 11;
    gu_body(XB, WGUT, comb, cnt, tok, ACTC, I_DIM / 64,
            (long long)(2 * I_DIM) * H_DIM, (long long)T_TOK * I_DIM, I_DIM,
            nx, my, e, SM);
  } else if (bid < MG_GUR_BLKS + MG_GUS_BLKS) {
    const int id = bid - MG_GUR_BLKS;
    gu_body(XB, WSGUT, nullptr, nullptr, nullptr, ACTS, IS_DIM / 64, 0, 0, IS_DIM,
            id % 22, id / 22, 0, SM);
  } else if (bid < MG_GUR_BLKS + MG_GUS_BLKS + MG_TWD_BLKS) {
    const int id = bid - MG_GUR_BLKS - MG_GUS_BLKS;
    const int e = id / 176;
    transp_tile_body(wd + (size_t)e * I_DIM * H_DIM,
                     WDT + (size_t)e * H_DIM * I_DIM, H_DIM, 11,
                     id % 16, (id / 16) % 11, SM);
  } else {
    const int id = bid - MG_GUR_BLKS - MG_GUS_BLKS - MG_TWD_BLKS;
    transp_tile_body(wsd, WSDT, H_DIM, 22, id % 16, id / 16, SM);
  }
}

// ---------------- down GEMM core: BM=64, BN=128, tile-blocked B, atomic ----------------
__device__ __forceinline__ void down_core_atomic(
    const u16* __restrict__ Ap, int astride, const u16* __restrict__ Bp, int NTK,
    int NT, int M, int m0, int n0, const int* tokS, float* __restrict__ outp) {
  __shared__ __align__(16) u16 S[12288]; // As 4096, Bs 8192
  const int tid = threadIdx.x;
  const int w = tid >> 6, l = tid & 63;
  const int r8 = l >> 3;
  const int sk = ((l & 7) ^ r8) * 8;

  size_t arow[2];
#pragma unroll
  for (int j = 0; j < 2; ++j) {
    const int m = w * 16 + j * 8 + r8;
    arow[j] = (size_t)(m0 + m < M ? m : (M - 1 - m0 > 0 ? M - 1 - m0 : 0)) * astride + sk;
  }
  size_t brow[4];
#pragma unroll
  for (int j = 0; j < 4; ++j) {
    const int row = w * 32 + j * 8 + r8; // 0..127 across BN=128 (2 n-tiles)
    brow[j] = (size_t)((row >> 6) * NTK) * 4096 + (row & 63) * 64 + sk;
  }

  const int fr = l & 15, fg = l >> 4;
  const f32x4 zero = {0.f, 0.f, 0.f, 0.f};
  f32x4 acc[4][2];
#pragma unroll
  for (int i = 0; i < 4; ++i)
#pragma unroll
    for (int j = 0; j < 2; ++j) acc[i][j] = zero;

  for (int kt = 0; kt < NT; ++kt) {
    const int k0 = kt * 64;
    const int tb = kt * 4096;
#pragma unroll
    for (int j = 0; j < 2; ++j)
      gload16(Ap + arow[j] + k0, S + (w * 2 + j) * 512);
#pragma unroll
    for (int j = 0; j < 4; ++j)
      gload16(Bp + brow[j] + tb, S + 4096 + (w * 4 + j) * 512);
    __syncthreads();
    const u16* AsC = S;
    const u16* BsC = S + 4096;
#pragma unroll
    for (int kk = 0; kk < 2; ++kk) {
      const int kb = kk * 64 + fg * 16;
      bf16x8 af[4], bfr[2];
#pragma unroll
      for (int mi = 0; mi < 4; ++mi)
        af[mi] = *(const bf16x8*)lds_sw(AsC, mi * 16 + fr, kb);
#pragma unroll
      for (int ni = 0; ni < 2; ++ni)
        bfr[ni] = *(const bf16x8*)lds_sw(BsC, w * 32 + ni * 16 + fr, kb);
#pragma unroll
      for (int mi = 0; mi < 4; ++mi)
#pragma unroll
        for (int ni = 0; ni < 2; ++ni) acc[mi][ni] = MFMA(af[mi], bfr[ni], acc[mi][ni]);
    }
    __syncthreads();
  }

#pragma unroll
  for (int mi = 0; mi < 4; ++mi) {
#pragma unroll
    for (int r = 0; r < 4; ++r) {
      const int ml = mi * 16 + fg * 4 + r;
      if (m0 + ml >= M) continue;
      float* op = outp + (size_t)tokS[ml] * H_DIM + n0 + w * 32;
#pragma unroll
      for (int ni = 0; ni < 2; ++ni)
        atomicAdd(op + ni * 16 + fr, acc[mi][ni][r]);
    }
  }
}

// single down launch: z=0..15 routed experts, z=16 shared; all atomic into
// the pre-zeroed output (zeroed by fused_pre_k; same-stream ordering).
__global__ __launch_bounds__(256, 4) void down_all_k(
    const u16* __restrict__ ACTC, const u16* __restrict__ WDT,
    const u16* __restrict__ ACTS, const u16* __restrict__ WSDT,
    const int* __restrict__ cnt, const int* __restrict__ tok,
    float* __restrict__ outp) {
  const int e = blockIdx.z;
  const bool shared = (e == E_NUM);
  const int M = shared ? T_TOK : cnt[e];
  const int m0 = blockIdx.y * 64;
  if (m0 >= M) return;
  const int n0 = blockIdx.x * 128;
  __shared__ int tokS[64];
  const int tid = threadIdx.x;
  if (tid < 64) {
    const int m = m0 + tid;
    tokS[tid] = shared ? m : tok[e * T_TOK + (m < M ? m : M - 1)];
  }
  __syncthreads();
  if (shared)
    down_core_atomic(ACTS + (size_t)m0 * IS_DIM, IS_DIM,
                     WSDT + (size_t)((n0 >> 6) * 22) * 4096, 22,
                     IS_DIM / 64, M, m0, n0, tokS, outp);
  else
    down_core_atomic(ACTC + ((size_t)e * T_TOK + m0) * I_DIM, I_DIM,
                     WDT + (size_t)e * H_DIM * I_DIM +
                         (size_t)((n0 >> 6) * 11) * 4096, 11,
                     I_DIM / 64, M, m0, n0, tokS, outp);
}

extern "C" void kernel_launch(void* const* d_in, const int* in_sizes, int n_in,
                              void* d_out, int out_size, void* d_ws, size_t ws_size,
                              hipStream_t stream) {
  const float* x    = (const float*)d_in[0];
  const float* wg   = (const float*)d_in[1];
  const float* wgu  = (const float*)d_in[2];
  const float* wd   = (const float*)d_in[3];
  const float* wsgu = (const float*)d_in[4];
  const float* wsd  = (const float*)d_in[5];
  float* out = (float*)d_out;

  char* ws = (char*)d_ws;
  size_t off = 0;
  auto alloc = [&](size_t b) { size_t r = off; off += (b + 255) & ~(size_t)255; return r; };
  u16*   XB    = (u16*)  (ws + alloc((size_t)T_TOK * H_DIM * 2));
  float* COMB  = (float*)(ws + alloc((size_t)T_TOK * E_NUM * 4));
  int*   CNT   = (int*)  (ws + alloc((size_t)E_NUM * 4));
  int*   TOK   = (int*)  (ws + alloc((size_t)E_NUM * T_TOK * 4));
  u16*   WGUT  = (u16*)  (ws + alloc((size_t)E_NUM * 2 * I_DIM * H_DIM * 2)); // tiled [e][22nt][32kt][4096]
  u16*   WDT   = (u16*)  (ws + alloc((size_t)E_NUM * H_DIM * I_DIM * 2));     // tiled [e][32nt][11kt][4096]
  u16*   WSGUT = (u16*)  (ws + alloc((size_t)2 * IS_DIM * H_DIM * 2));        // tiled [44nt][32kt][4096]
  u16*   WSDT  = (u16*)  (ws + alloc((size_t)H_DIM * IS_DIM * 2));            // tiled [32nt][22kt][4096]
  u16*   ACTC  = (u16*)  (ws + alloc((size_t)E_NUM * T_TOK * I_DIM * 2));     // [e][1024][704]
  u16*   ACTS  = (u16*)  (ws + alloc((size_t)T_TOK * IS_DIM * 2));            // [1024][1408]
  if (ws_size < off) return;

  // fused pre-pass: router (+x->bf16) + out-zero + wgu/wsgu tile-transposes
  fused_pre_k<<<FP_ROUTER + FP_ZERO + FP_WGU + FP_WSGU, 256, 0, stream>>>(
      x, wg, COMB, XB, wgu, wsgu, WGUT, WSGUT, out);
  dispatch_k<<<E_NUM, 256, 0, stream>>>(COMB, CNT, TOK);
  // mega: routed gu (XCD-clustered) + shared gu + wd/wsd tile-transposes
  mega_k<<<MG_GUR_BLKS + MG_GUS_BLKS + MG_TWD_BLKS + MG_TWSD_BLKS, 256, 0, stream>>>(
      XB, WGUT, WSGUT, COMB, CNT, TOK, ACTC, ACTS, wd, wsd, WDT, WSDT);
  // single all-atomic down pass (routed z=0..15, shared z=16) into zeroed out
  down_all_k<<<dim3(H_DIM / 128, T_TOK / 64, E_NUM + 1), 256, 0, stream>>>(
      ACTC, WDT, ACTS, WSDT, CNT, TOK, out);
}